// Round 10
// baseline (411.567 us; speedup 1.0000x reference)
//
#include <hip/hip_runtime.h>
#include <math.h>

#define TPB   128     // scalar fallback
#define HTPB  256
#define HPTS  4       // points per thread in hash kernel
#define CHUNK 32
#define LDW   68      // f32 LDS row stride: 272 B, 16B-aligned
constexpr int  N_LVL = 16;
constexpr unsigned TBL = 1u << 19;
constexpr float MOVE_STEP = 1.0f / 4096.0f;

typedef __attribute__((ext_vector_type(8))) short short8;
typedef __attribute__((ext_vector_type(4))) float f32x4;

struct LevelParams { float scale[N_LVL]; int res[N_LVL]; int dense[N_LVL]; };

// weight-fragment chunks (2048 B each = hi[64 lanes][short8] + lo[...])
enum { C_W0 = 0, C_W1 = 4, C_W2 = 12, C_B0 = 14, C_B1 = 18, C_H0 = 20, C_H1 = 24, C_H2 = 32, C_TOT = 34 };

struct LayerDesc { const float* W; int K; int N; int ksteps; int ntiles; int cbase; };
struct AllLayers { LayerDesc L[8]; };

__device__ __forceinline__ unsigned short f2bf(float x) {
    unsigned int u = __float_as_uint(x);
    u += 0x7FFFu + ((u >> 16) & 1u);            // RNE
    return (unsigned short)(u >> 16);
}
__device__ __forceinline__ float bf2f(unsigned short h) {
    return __uint_as_float(((unsigned int)h) << 16);
}

// hw RNE pack: bf16(a) in [15:0], bf16(b) in [31:16]
__device__ __forceinline__ unsigned cvt_pk_bf16(float a, float b) {
    unsigned r;
    asm("v_cvt_pk_bf16_f32 %0, %1, %2" : "=v"(r) : "v"(a), "v"(b));
    return r;
}
// RNE hi/lo split of a float pair via cvt_pk. Same RNE as f2bf; residual exact.
__device__ __forceinline__ void split_pair(float a, float b, unsigned& hp, unsigned& lp) {
    hp = cvt_pk_bf16(a, b);
    const float ha = __uint_as_float(hp << 16);
    const float hb = __uint_as_float(hp & 0xffff0000u);
    lp = cvt_pk_bf16(a - ha, b - hb);
}

// ---------------------------------------------------------------------------
// prep: split weights into bf16 (hi,lo) MFMA B-fragments (RNE), per-lane order
// ---------------------------------------------------------------------------
__global__ __launch_bounds__(256) void k_prep(AllLayers al, unsigned short* __restrict__ wfrag)
{
    const LayerDesc d = al.L[blockIdx.x];
    const int total = d.ksteps * d.ntiles * 64;
    for (int slot = threadIdx.x; slot < total; slot += 256) {
        const int lane = slot & 63;
        const int c = slot >> 6;
        const int s = c / d.ntiles;
        const int t = c - s * d.ntiles;
        short8 hv, lv;
#pragma unroll
        for (int j = 0; j < 8; ++j) {
            const int k = s * 32 + ((lane >> 4) << 3) + j;
            const int n = t * 16 + (lane & 15);
            const float w = (k < d.K && n < d.N) ? d.W[k * d.N + n] : 0.f;
            const unsigned short hi = f2bf(w);
            const unsigned short lo = f2bf(w - bf2f(hi));
            hv[j] = (short)hi;
            lv[j] = (short)lo;
        }
        short8* b8 = reinterpret_cast<short8*>(wfrag + (size_t)(d.cbase + c) * 1024);
        b8[lane]      = hv;
        b8[64 + lane] = lv;
    }
}

// ---------------------------------------------------------------------------
// wave dense layer: f32 LDS in, per-k-step RNE hi/lo split (cvt_pk), 3-term
// MFMA (hh + lh + hl), f32 LDS out. In-place on one buffer (proven R7).
// ---------------------------------------------------------------------------
template<int KSTEPS, int NTILES, bool RELU>
__device__ __forceinline__ void wave_layer(float* X,
                                           const unsigned short* __restrict__ wfrag, int cbase,
                                           int wrow, int lane)
{
    f32x4 acc[2][NTILES];
#pragma unroll
    for (int ms = 0; ms < 2; ++ms)
#pragma unroll
        for (int t = 0; t < NTILES; ++t) acc[ms][t] = f32x4{0.f, 0.f, 0.f, 0.f};
    const int r15 = lane & 15, q = lane >> 4;
    const short8* wf8 = reinterpret_cast<const short8*>(wfrag) + (size_t)cbase * 128;
#pragma unroll
    for (int s = 0; s < KSTEPS; ++s) {
        short8 ah[2], al[2];
#pragma unroll
        for (int ms = 0; ms < 2; ++ms) {
            const float* xp = X + (size_t)(wrow + ms * 16 + r15) * LDW + s * 32 + q * 8;
            const f32x4 x0 = reinterpret_cast<const f32x4*>(xp)[0];
            const f32x4 x1 = reinterpret_cast<const f32x4*>(xp)[1];
            union { unsigned u[4]; short8 s8; } uh, ul;
            split_pair(x0[0], x0[1], uh.u[0], ul.u[0]);
            split_pair(x0[2], x0[3], uh.u[1], ul.u[1]);
            split_pair(x1[0], x1[1], uh.u[2], ul.u[2]);
            split_pair(x1[2], x1[3], uh.u[3], ul.u[3]);
            ah[ms] = uh.s8;
            al[ms] = ul.s8;
        }
#pragma unroll
        for (int t = 0; t < NTILES; ++t) {
            const short8* cp = wf8 + (size_t)(s * NTILES + t) * 128;
            const short8 bh = cp[lane];
            const short8 bl = cp[64 + lane];
#pragma unroll
            for (int ms = 0; ms < 2; ++ms) {
                acc[ms][t] = __builtin_amdgcn_mfma_f32_16x16x32_bf16(ah[ms], bh, acc[ms][t], 0, 0, 0);
                acc[ms][t] = __builtin_amdgcn_mfma_f32_16x16x32_bf16(al[ms], bh, acc[ms][t], 0, 0, 0);
                acc[ms][t] = __builtin_amdgcn_mfma_f32_16x16x32_bf16(ah[ms], bl, acc[ms][t], 0, 0, 0);
            }
        }
    }
#pragma unroll
    for (int ms = 0; ms < 2; ++ms)
#pragma unroll
        for (int t = 0; t < NTILES; ++t)
#pragma unroll
            for (int r = 0; r < 4; ++r) {
                float v = acc[ms][t][r];
                if (RELU) v = fmaxf(v, 0.f);
                X[(size_t)(wrow + ms * 16 + q * 4 + r) * LDW + t * 16 + r15] = v;
            }
}

// ---------------------------------------------------------------------------
// Kernel 1: freq encode + warp MLP (MFMA) -> xn planes + DENSE hash levels
// ---------------------------------------------------------------------------
__global__ __launch_bounds__(256, 4) void k_warp_mfma(
    const float* __restrict__ g_pos, const float* __restrict__ g_t,
    const float* __restrict__ g_tab,
    const unsigned short* __restrict__ wfrag,
    float* __restrict__ xn0, float* __restrict__ xn1, float* __restrict__ xn2,
    float* __restrict__ featp, size_t stride, int N, int n_dense, LevelParams lp)
{
    __shared__ float buf[128 * LDW];        // 34.8 KB
    const int tid = threadIdx.x;
    const int base = blockIdx.x * 128;
    const int p = tid & 127;
    const int pn = min(base + p, N - 1);
    const float PI_F = 3.14159265358979323846f;

    {   // enc staging: thread-pairs split the 4 input dims
        const int dpair = tid >> 7;
        float v0, v1;
        if (dpair == 0) { v0 = g_pos[3 * pn + 0]; v1 = g_pos[3 * pn + 1]; }
        else            { v0 = g_pos[3 * pn + 2]; v1 = g_t[pn]; }
#pragma unroll
        for (int e = 0; e < 2; ++e) {
            const float x = e ? v1 : v0;
            const int d = dpair * 2 + e;
            f32x4 sv, cv;
#pragma unroll
            for (int k = 0; k < 4; ++k) {
                const float a = x * (PI_F * (float)(1 << k));
                sv[k] = __sinf(a);
                cv[k] = __cosf(a);
            }
            *reinterpret_cast<f32x4*>(&buf[(size_t)p * LDW + d * 8])     = sv;
            *reinterpret_cast<f32x4*>(&buf[(size_t)p * LDW + d * 8 + 4]) = cv;
        }
    }
    __syncthreads();
    const int lane = tid & 63, wrow = (tid >> 6) * 32;
    wave_layer<1, 4, true >(buf, wfrag, C_W0, wrow, lane);
    wave_layer<2, 4, true >(buf, wfrag, C_W1, wrow, lane);
    wave_layer<2, 1, false>(buf, wfrag, C_W2, wrow, lane);
    __syncthreads();

    // ---- epilogue: xn (both halves compute; half 0 stores) + dense levels
    const int n = base + p;
    const float ox = buf[(size_t)p * LDW + 0];
    const float oy = buf[(size_t)p * LDW + 1];
    const float oz = buf[(size_t)p * LDW + 2];
    const float xnv[3] = { (g_pos[3 * pn + 0] + ox * MOVE_STEP + 1.5f) / 3.0f,
                           (g_pos[3 * pn + 1] + oy * MOVE_STEP + 1.5f) / 3.0f,
                           (g_pos[3 * pn + 2] + oz * MOVE_STEP + 1.5f) / 3.0f };
    if (tid < 128 && n < N) {
        xn0[n] = xnv[0];
        xn1[n] = xnv[1];
        xn2[n] = xnv[2];
    }

    const int dmid = min(3, n_dense);
    const int l0 = (tid < 128) ? 0 : dmid;
    const int l1 = (tid < 128) ? dmid : n_dense;
    for (int l = l0; l < l1; ++l) {
        const float scale = lp.scale[l];
        const int res = lp.res[l];
        float fr[3]; int c0[3];
#pragma unroll
        for (int d = 0; d < 3; ++d) {
            const float pp = xnv[d] * scale + 0.5f;
            const float fl = floorf(pp);
            fr[d] = pp - fl;
            c0[d] = (int)fl;
        }
        const float* __restrict__ tbl = g_tab + (size_t)l * (size_t)(TBL * 2);
        float2 v[8];
#pragma unroll
        for (int c = 0; c < 8; ++c) {
            const int ci = (c >> 2) & 1, cj = (c >> 1) & 1, ck = c & 1;
            const unsigned idx = (unsigned)((c0[0] + ci) + res * ((c0[1] + cj) + res * (c0[2] + ck)));
            v[c] = *reinterpret_cast<const float2*>(tbl + (size_t)idx * 2);
        }
        float f0 = 0.f, f1 = 0.f;
#pragma unroll
        for (int c = 0; c < 8; ++c) {
            const int ci = (c >> 2) & 1, cj = (c >> 1) & 1, ck = c & 1;
            const float w = (ci ? fr[0] : 1.f - fr[0])
                          * (cj ? fr[1] : 1.f - fr[1])
                          * (ck ? fr[2] : 1.f - fr[2]);
            f0 = fmaf(w, v[c].x, f0);
            f1 = fmaf(w, v[c].y, f1);
        }
        if (n < N) {
            __builtin_nontemporal_store(f0, &featp[(size_t)(2 * l)     * stride + n]);
            __builtin_nontemporal_store(f1, &featp[(size_t)(2 * l + 1) * stride + n]);
        }
    }
}

// ---------------------------------------------------------------------------
// Kernel 2: ALL hashed levels, one launch, XCD-partitioned level ownership.
// Work item w = level*nchunk + chunk (C total). XCD x (= blockIdx%8 under the
// round-robin dispatch heuristic) owns contiguous range [x*Q, (x+1)*Q), so
// each 4MB table is filled by <=2 XCDs (vs all 8) and each XCD walks its
// levels sequentially -> its L2 holds one table at a time (~98% hit).
// Math identical to R9; only the block->work mapping changed.
// ---------------------------------------------------------------------------
__global__ __launch_bounds__(HTPB, 8) void k_hash_all(
    const float* __restrict__ g_tab,
    const float* __restrict__ xn0, const float* __restrict__ xn1,
    const float* __restrict__ xn2,
    float* __restrict__ featp, size_t stride, int N, int n_dense,
    int nchunk, int Q, int C, LevelParams lp)
{
    const int bid = blockIdx.x;
    const int w = (bid & 7) * Q + (bid >> 3);
    if (w >= C) return;
    const int li = w / nchunk;
    const int chunk = w - li * nchunk;
    const int l = n_dense + li;

    const float scale = lp.scale[l];
    const float* __restrict__ tbl = g_tab + (size_t)l * (size_t)(TBL * 2);
    float* __restrict__ o0 = featp + (size_t)(2 * l)     * stride;
    float* __restrict__ o1 = featp + (size_t)(2 * l + 1) * stride;

    const int base = chunk * (HTPB * HPTS) + threadIdx.x;

    int nn[HPTS]; bool av[HPTS];
    float xs[HPTS][3];
#pragma unroll
    for (int k = 0; k < HPTS; ++k) {
        nn[k] = base + k * HTPB;
        av[k] = nn[k] < N;
        const int m = av[k] ? nn[k] : 0;
        xs[k][0] = __builtin_nontemporal_load(&xn0[m]);
        xs[k][1] = __builtin_nontemporal_load(&xn1[m]);
        xs[k][2] = __builtin_nontemporal_load(&xn2[m]);
    }

    float fr[HPTS][3];
    float2 v[HPTS][8];
#pragma unroll
    for (int k = 0; k < HPTS; ++k) {
        int c0[3];
#pragma unroll
        for (int d = 0; d < 3; ++d) {
            const float pp = xs[k][d] * scale + 0.5f;
            const float fl = floorf(pp);
            fr[k][d] = pp - fl;
            c0[d] = (int)fl;
        }
#pragma unroll
        for (int c = 0; c < 8; ++c) {
            const int ci = (c >> 2) & 1, cj = (c >> 1) & 1, ck = c & 1;
            const unsigned idx = (((unsigned)(c0[0] + ci)) ^ ((unsigned)(c0[1] + cj) * 2654435761u)
                                  ^ ((unsigned)(c0[2] + ck) * 805459861u)) & (TBL - 1u);
            v[k][c] = *reinterpret_cast<const float2*>(tbl + (size_t)idx * 2);
        }
    }

#pragma unroll
    for (int k = 0; k < HPTS; ++k) {
        float f0 = 0.f, f1 = 0.f;
#pragma unroll
        for (int c = 0; c < 8; ++c) {
            const int ci = (c >> 2) & 1, cj = (c >> 1) & 1, ck = c & 1;
            const float w2 = (ci ? fr[k][0] : 1.f - fr[k][0])
                           * (cj ? fr[k][1] : 1.f - fr[k][1])
                           * (ck ? fr[k][2] : 1.f - fr[k][2]);
            f0 = fmaf(w2, v[k][c].x, f0);
            f1 = fmaf(w2, v[k][c].y, f1);
        }
        if (av[k]) {
            __builtin_nontemporal_store(f0, &o0[nn[k]]);
            __builtin_nontemporal_store(f1, &o1[nn[k]]);
        }
    }
}

// ---------------------------------------------------------------------------
// Kernel 3: base MLP + SH + head MLP (MFMA) -> output
// ---------------------------------------------------------------------------
__global__ __launch_bounds__(256, 4) void k_final_mfma(
    const float* __restrict__ featp, size_t stride,
    const float* __restrict__ xn0, const float* __restrict__ xn1,
    const float* __restrict__ xn2,
    const float* __restrict__ g_dir,
    const unsigned short* __restrict__ wfrag,
    float* __restrict__ g_out, int N)
{
    __shared__ float buf[128 * LDW];        // 34.8 KB
    const int tid = threadIdx.x;
    const int base = blockIdx.x * 128;
    const int p = tid & 127;
    const int pn = min(base + p, N - 1);
    const int fb = (tid >> 7) * 16;

    // stage 32 f32 feat planes -> buf[p][0..31]
#pragma unroll
    for (int j = 0; j < 16; ++j)
        buf[(size_t)p * LDW + fb + j] = featp[(size_t)(fb + j) * stride + pn];
    __syncthreads();

    const int lane = tid & 63, wrow = (tid >> 6) * 32;
    wave_layer<1, 4, true >(buf, wfrag, C_B0, wrow, lane);
    wave_layer<2, 1, false>(buf, wfrag, C_B1, wrow, lane);
    __syncthreads();

    float density = 0.f;
    if (tid < 128) {
        float bb[16];
        const f32x4* bv = reinterpret_cast<const f32x4*>(&buf[(size_t)tid * LDW]);
#pragma unroll
        for (int g4 = 0; g4 < 4; ++g4) {
            const f32x4 v = bv[g4];
#pragma unroll
            for (int j = 0; j < 4; ++j) bb[4 * g4 + j] = v[j];
        }
        const float x0v = xn0[pn], x1v = xn1[pn], x2v = xn2[pn];
        const bool sel = x0v > 0.f && x0v < 1.f && x1v > 0.f && x1v < 1.f &&
                         x2v > 0.f && x2v < 1.f;
        density = sel ? expf(bb[0] - 1.0f) : 0.0f;

        const float ddx = g_dir[3 * pn + 0];
        const float ddy = g_dir[3 * pn + 1];
        const float ddz = g_dir[3 * pn + 2];
        const float nrm = sqrtf(ddx * ddx + ddy * ddy + ddz * ddz);
        const float x = ddx / nrm, y = ddy / nrm, z = ddz / nrm;
        const float xy = x * y, yz = y * z, xz = x * z;
        const float x2 = x * x, y2 = y * y, z2 = z * z;
        f32x4 o0, o1, o2, o3, o4, o5, o6, o7;
        o0[0] = 0.28209479177387814f;
        o0[1] = -0.48860251190291987f * y;
        o0[2] = 0.48860251190291987f * z;
        o0[3] = -0.48860251190291987f * x;
        o1[0] = 1.0925484305920792f * xy;
        o1[1] = -1.0925484305920792f * yz;
        o1[2] = 0.94617469575756f * z2 - 0.31539156525252f;
        o1[3] = -1.0925484305920792f * xz;
        o2[0] = 0.5462742152960396f * (x2 - y2);
        o2[1] = 0.5900435899266435f * y * (y2 - 3.0f * x2);
        o2[2] = 2.890611442640554f * xy * z;
        o2[3] = 0.4570457994644657f * y * (1.0f - 5.0f * z2);
        o3[0] = 0.3731763325901154f * z * (5.0f * z2 - 3.0f);
        o3[1] = 0.4570457994644657f * x * (1.0f - 5.0f * z2);
        o3[2] = 1.445305721320277f * z * (x2 - y2);
        o3[3] = 0.5900435899266435f * x * (3.0f * y2 - x2);
        o4[0] = bb[1];  o4[1] = bb[2];  o4[2] = bb[3];  o4[3] = bb[4];
        o5[0] = bb[5];  o5[1] = bb[6];  o5[2] = bb[7];  o5[3] = bb[8];
        o6[0] = bb[9];  o6[1] = bb[10]; o6[2] = bb[11]; o6[3] = bb[12];
        o7[0] = bb[13]; o7[1] = bb[14]; o7[2] = bb[15]; o7[3] = 0.f;
        f32x4* wb = reinterpret_cast<f32x4*>(&buf[(size_t)tid * LDW]);
        wb[0] = o0; wb[1] = o1; wb[2] = o2; wb[3] = o3;
        wb[4] = o4; wb[5] = o5; wb[6] = o6; wb[7] = o7;
    }
    __syncthreads();

    wave_layer<1, 4, true >(buf, wfrag, C_H0, wrow, lane);
    wave_layer<2, 4, true >(buf, wfrag, C_H1, wrow, lane);
    wave_layer<2, 1, false>(buf, wfrag, C_H2, wrow, lane);
    __syncthreads();

    if (tid < 128 && base + tid < N) {
        const int n = base + tid;
        float4 o;
        o.x = 1.0f / (1.0f + expf(-buf[(size_t)tid * LDW + 0]));
        o.y = 1.0f / (1.0f + expf(-buf[(size_t)tid * LDW + 1]));
        o.z = 1.0f / (1.0f + expf(-buf[(size_t)tid * LDW + 2]));
        o.w = density;
        *reinterpret_cast<float4*>(g_out + (size_t)n * 4) = o;
    }
}

// ---------------------------------------------------------------------------
// Scalar fallback (round-2 monolith) used only if ws too small
// ---------------------------------------------------------------------------
template<int IN, int OUT, bool RELU>
__device__ __forceinline__ void layer(const float* __restrict__ W,
                                      const float* __restrict__ hin,
                                      float* __restrict__ A,
                                      float* __restrict__ out)
{
#pragma unroll
    for (int j = 0; j < OUT; ++j) out[j] = 0.f;
#pragma unroll
    for (int c = 0; c < IN; c += CHUNK) {
#pragma unroll
        for (int i = 0; i < CHUNK; ++i) {
            if (c + i < IN) A[i * TPB] = RELU ? fmaxf(hin[c + i], 0.f) : hin[c + i];
        }
        const int cnt = (IN - c < CHUNK) ? (IN - c) : CHUNK;
#pragma unroll 4
        for (int i = 0; i < cnt; ++i) {
            const float a = A[i * TPB];
            const float* __restrict__ Wr = W + (size_t)(c + i) * OUT;
#pragma unroll
            for (int j = 0; j < OUT; ++j)
                out[j] = fmaf(a, Wr[j], out[j]);
        }
    }
}

__global__ __launch_bounds__(TPB, 4) void dngp_mono(
    const float* __restrict__ g_pos, const float* __restrict__ g_t,
    const float* __restrict__ g_dir, const float* __restrict__ g_tab,
    const float* __restrict__ Ww0, const float* __restrict__ Ww1, const float* __restrict__ Ww2,
    const float* __restrict__ Wb0, const float* __restrict__ Wb1,
    const float* __restrict__ Wh0, const float* __restrict__ Wh1, const float* __restrict__ Wh2,
    float* __restrict__ g_out, int N, LevelParams lp)
{
    __shared__ float s_act[CHUNK * TPB];
    const int tid = threadIdx.x;
    const int n = blockIdx.x * TPB + tid;
    if (n >= N) return;
    float* __restrict__ A = s_act + tid;

    const float px = g_pos[3 * n + 0];
    const float py = g_pos[3 * n + 1];
    const float pz = g_pos[3 * n + 2];
    const float tt = g_t[n];

    float enc[32];
    {
        const float xin[4] = { px, py, pz, tt };
        const float PI_F = 3.14159265358979323846f;
#pragma unroll
        for (int d = 0; d < 4; ++d)
#pragma unroll
            for (int k = 0; k < 4; ++k) {
                float s, c;
                sincosf(xin[d] * (PI_F * (float)(1 << k)), &s, &c);
                enc[d * 8 + k]     = s;
                enc[d * 8 + 4 + k] = c;
            }
    }

    float h[64], h2[64], off[3];
    layer<32, 64, false>(Ww0, enc, A, h);
    layer<64, 64, true >(Ww1, h,   A, h2);
    layer<64, 3,  true >(Ww2, h2,  A, off);

    const float xn[3] = { (px + off[0] * MOVE_STEP + 1.5f) / 3.0f,
                          (py + off[1] * MOVE_STEP + 1.5f) / 3.0f,
                          (pz + off[2] * MOVE_STEP + 1.5f) / 3.0f };
    const bool sel = xn[0] > 0.f && xn[0] < 1.f && xn[1] > 0.f && xn[1] < 1.f &&
                     xn[2] > 0.f && xn[2] < 1.f;

    float feat[32];
#pragma unroll 2
    for (int l = 0; l < N_LVL; ++l) {
        const float scale = lp.scale[l];
        const int res = lp.res[l];
        float fr[3]; int c0[3];
#pragma unroll
        for (int d = 0; d < 3; ++d) {
            const float pp = xn[d] * scale + 0.5f;
            const float fl = floorf(pp);
            fr[d] = pp - fl;
            c0[d] = (int)fl;
        }
        const float* __restrict__ tbl = g_tab + (size_t)l * (size_t)(TBL * 2);
        float f0 = 0.f, f1 = 0.f;
        if (lp.dense[l]) {
#pragma unroll
            for (int c = 0; c < 8; ++c) {
                const int ci = (c >> 2) & 1, cj = (c >> 1) & 1, ck = c & 1;
                const unsigned idx = (unsigned)((c0[0] + ci) + res * ((c0[1] + cj) + res * (c0[2] + ck)));
                const float2 f = *reinterpret_cast<const float2*>(tbl + (size_t)idx * 2);
                const float w = (ci ? fr[0] : 1.f - fr[0]) * (cj ? fr[1] : 1.f - fr[1]) * (ck ? fr[2] : 1.f - fr[2]);
                f0 = fmaf(w, f.x, f0);
                f1 = fmaf(w, f.y, f1);
            }
        } else {
#pragma unroll
            for (int c = 0; c < 8; ++c) {
                const int ci = (c >> 2) & 1, cj = (c >> 1) & 1, ck = c & 1;
                const unsigned hx = (unsigned)(c0[0] + ci);
                const unsigned hy = (unsigned)(c0[1] + cj) * 2654435761u;
                const unsigned hz = (unsigned)(c0[2] + ck) * 805459861u;
                const unsigned idx = (hx ^ hy ^ hz) & (TBL - 1u);
                const float2 f = *reinterpret_cast<const float2*>(tbl + (size_t)idx * 2);
                const float w = (ci ? fr[0] : 1.f - fr[0]) * (cj ? fr[1] : 1.f - fr[1]) * (ck ? fr[2] : 1.f - fr[2]);
                f0 = fmaf(w, f.x, f0);
                f1 = fmaf(w, f.y, f1);
            }
        }
        feat[2 * l]     = f0;
        feat[2 * l + 1] = f1;
    }

    layer<32, 64, false>(Wb0, feat, A, h);
    float b[16];
    layer<64, 16, true >(Wb1, h, A, b);
    const float density = sel ? expf(b[0] - 1.0f) : 0.0f;

    float hin[31];
    {
        const float ddx = g_dir[3 * n + 0];
        const float ddy = g_dir[3 * n + 1];
        const float ddz = g_dir[3 * n + 2];
        const float nrm = sqrtf(ddx * ddx + ddy * ddy + ddz * ddz);
        const float x = ddx / nrm, y = ddy / nrm, z = ddz / nrm;
        const float xy = x * y, yz = y * z, xz = x * z;
        const float x2_ = x * x, y2 = y * y, z2 = z * z;
        hin[0]  = 0.28209479177387814f;
        hin[1]  = -0.48860251190291987f * y;
        hin[2]  = 0.48860251190291987f * z;
        hin[3]  = -0.48860251190291987f * x;
        hin[4]  = 1.0925484305920792f * xy;
        hin[5]  = -1.0925484305920792f * yz;
        hin[6]  = 0.94617469575756f * z2 - 0.31539156525252f;
        hin[7]  = -1.0925484305920792f * xz;
        hin[8]  = 0.5462742152960396f * (x2_ - y2);
        hin[9]  = 0.5900435899266435f * y * (y2 - 3.0f * x2_);
        hin[10] = 2.890611442640554f * xy * z;
        hin[11] = 0.4570457994644657f * y * (1.0f - 5.0f * z2);
        hin[12] = 0.3731763325901154f * z * (5.0f * z2 - 3.0f);
        hin[13] = 0.4570457994644657f * x * (1.0f - 5.0f * z2);
        hin[14] = 1.445305721320277f * z * (x2_ - y2);
        hin[15] = 0.5900435899266435f * x * (3.0f * y2 - x2_);
#pragma unroll
        for (int j = 0; j < 15; ++j) hin[16 + j] = b[1 + j];
    }

    layer<31, 64, false>(Wh0, hin, A, h);
    layer<64, 64, true >(Wh1, h,   A, h2);
    float rgb[3];
    layer<64, 3,  true >(Wh2, h2,  A, rgb);

    float4 o;
    o.x = 1.0f / (1.0f + expf(-rgb[0]));
    o.y = 1.0f / (1.0f + expf(-rgb[1]));
    o.z = 1.0f / (1.0f + expf(-rgb[2]));
    o.w = density;
    *reinterpret_cast<float4*>(g_out + (size_t)n * 4) = o;
}

extern "C" void kernel_launch(void* const* d_in, const int* in_sizes, int n_in,
                              void* d_out, int out_size, void* d_ws, size_t ws_size,
                              hipStream_t stream)
{
    const float* g_pos = (const float*)d_in[0];
    const float* g_t   = (const float*)d_in[1];
    const float* g_dir = (const float*)d_in[2];
    const float* g_tab = (const float*)d_in[3];
    const float* Ww0   = (const float*)d_in[4];
    const float* Ww1   = (const float*)d_in[5];
    const float* Ww2   = (const float*)d_in[6];
    const float* Wb0   = (const float*)d_in[7];
    const float* Wb1   = (const float*)d_in[8];
    const float* Wh0   = (const float*)d_in[9];
    const float* Wh1   = (const float*)d_in[10];
    const float* Wh2   = (const float*)d_in[11];
    const int N = in_sizes[0] / 3;

    LevelParams lp;
    int n_dense = 0;
    const double Bv = exp(log(4096.0 / 16.0) / 15.0);
    for (int l = 0; l < N_LVL; ++l) {
        const double s = 16.0 * pow(Bv, (double)l) - 1.0;
        lp.scale[l] = (float)s;
        const int r = (int)ceil(s) + 1;
        lp.res[l] = r;
        lp.dense[l] = ((long long)r * r * r <= (long long)TBL) ? 1 : 0;
        if (lp.dense[l]) n_dense = l + 1;
    }

    const size_t stride = ((size_t)N + 259) & ~(size_t)3;
    const size_t ws_need = (size_t)C_TOT * 2048 + stride * 4 * (3 + 32);

    if (ws_size >= ws_need) {
        unsigned short* wfrag = (unsigned short*)d_ws;
        float* xn0 = (float*)((char*)d_ws + (size_t)C_TOT * 2048);
        float* xn1 = xn0 + stride;
        float* xn2 = xn1 + stride;
        float* featp = xn2 + stride;                          // 32 f32 planes

        AllLayers al;
        al.L[0] = { Ww0, 32, 64, 1, 4, C_W0 };
        al.L[1] = { Ww1, 64, 64, 2, 4, C_W1 };
        al.L[2] = { Ww2, 64,  3, 2, 1, C_W2 };
        al.L[3] = { Wb0, 32, 64, 1, 4, C_B0 };
        al.L[4] = { Wb1, 64, 16, 2, 1, C_B1 };
        al.L[5] = { Wh0, 31, 64, 1, 4, C_H0 };
        al.L[6] = { Wh1, 64, 64, 2, 4, C_H1 };
        al.L[7] = { Wh2, 64,  3, 2, 1, C_H2 };

        const int nchunk = (N + HTPB * HPTS - 1) / (HTPB * HPTS);
        const int C = (N_LVL - n_dense) * nchunk;
        const int Q = (C + 7) / 8;

        dim3 mgrid((N + 127) / 128), mblock(256);
        dim3 hgrid(Q * 8), hblock(HTPB);

        hipLaunchKernelGGL(k_prep, dim3(8), dim3(256), 0, stream, al, wfrag);

        hipLaunchKernelGGL(k_warp_mfma, mgrid, mblock, 0, stream,
                           g_pos, g_t, g_tab, wfrag, xn0, xn1, xn2,
                           featp, stride, N, n_dense, lp);

        hipLaunchKernelGGL(k_hash_all, hgrid, hblock, 0, stream,
                           g_tab, xn0, xn1, xn2, featp, stride, N, n_dense,
                           nchunk, Q, C, lp);

        hipLaunchKernelGGL(k_final_mfma, mgrid, mblock, 0, stream,
                           featp, stride, xn0, xn1, xn2, g_dir,
                           wfrag, (float*)d_out, N);
    } else {
        dim3 grid((N + TPB - 1) / TPB), block(TPB);
        hipLaunchKernelGGL(dngp_mono, grid, block, 0, stream,
                           g_pos, g_t, g_dir, g_tab,
                           Ww0, Ww1, Ww2, Wb0, Wb1, Wh0, Wh1, Wh2,
                           (float*)d_out, N, lp);
    }
}

// Round 11
// 308.552 us; speedup vs baseline: 1.3339x; 1.3339x over previous
//
#include <hip/hip_runtime.h>
#include <math.h>

#define TPB   128     // scalar fallback
#define HTPB  256
#define HPTS  4       // points per thread in hash kernel
#define CHUNK 32
#define LDW   68      // f32 LDS row stride: 272 B, 16B-aligned
constexpr int  N_LVL = 16;
constexpr unsigned TBL = 1u << 19;
constexpr float MOVE_STEP = 1.0f / 4096.0f;

typedef __attribute__((ext_vector_type(8))) short short8;
typedef __attribute__((ext_vector_type(4))) float f32x4;

struct LevelParams { float scale[N_LVL]; int res[N_LVL]; int dense[N_LVL]; };

// weight-fragment chunks (2048 B each = hi[64 lanes][short8] + lo[...])
enum { C_W0 = 0, C_W1 = 4, C_W2 = 12, C_B0 = 14, C_B1 = 18, C_H0 = 20, C_H1 = 24, C_H2 = 32, C_TOT = 34 };

struct LayerDesc { const float* W; int K; int N; int ksteps; int ntiles; int cbase; };
struct AllLayers { LayerDesc L[8]; };

__device__ __forceinline__ unsigned short f2bf(float x) {
    unsigned int u = __float_as_uint(x);
    u += 0x7FFFu + ((u >> 16) & 1u);            // RNE
    return (unsigned short)(u >> 16);
}
__device__ __forceinline__ float bf2f(unsigned short h) {
    return __uint_as_float(((unsigned int)h) << 16);
}
__device__ __forceinline__ unsigned pk(unsigned short a, unsigned short b) {
    return (unsigned)a | ((unsigned)b << 16);
}

// hw RNE pack: bf16(a) in [15:0], bf16(b) in [31:16]
__device__ __forceinline__ unsigned cvt_pk_bf16(float a, float b) {
    unsigned r;
    asm("v_cvt_pk_bf16_f32 %0, %1, %2" : "=v"(r) : "v"(a), "v"(b));
    return r;
}
// RNE hi/lo split of a float pair via cvt_pk. Same RNE as f2bf; residual exact.
__device__ __forceinline__ void split_pair(float a, float b, unsigned& hp, unsigned& lp) {
    hp = cvt_pk_bf16(a, b);
    const float ha = __uint_as_float(hp << 16);
    const float hb = __uint_as_float(hp & 0xffff0000u);
    lp = cvt_pk_bf16(a - ha, b - hb);
}

// ---------------------------------------------------------------------------
// prep: split weights into bf16 (hi,lo) MFMA B-fragments (RNE), per-lane order
// ---------------------------------------------------------------------------
__global__ __launch_bounds__(256) void k_prep(AllLayers al, unsigned short* __restrict__ wfrag)
{
    const LayerDesc d = al.L[blockIdx.x];
    const int total = d.ksteps * d.ntiles * 64;
    for (int slot = threadIdx.x; slot < total; slot += 256) {
        const int lane = slot & 63;
        const int c = slot >> 6;
        const int s = c / d.ntiles;
        const int t = c - s * d.ntiles;
        short8 hv, lv;
#pragma unroll
        for (int j = 0; j < 8; ++j) {
            const int k = s * 32 + ((lane >> 4) << 3) + j;
            const int n = t * 16 + (lane & 15);
            const float w = (k < d.K && n < d.N) ? d.W[k * d.N + n] : 0.f;
            const unsigned short hi = f2bf(w);
            const unsigned short lo = f2bf(w - bf2f(hi));
            hv[j] = (short)hi;
            lv[j] = (short)lo;
        }
        short8* b8 = reinterpret_cast<short8*>(wfrag + (size_t)(d.cbase + c) * 1024);
        b8[lane]      = hv;
        b8[64 + lane] = lv;
    }
}

// ---------------------------------------------------------------------------
// prep 2: convert hashed-level tables (levels n_dense..15) to packed bf16x2.
// Entry e of level l -> tab16[(l-n_dense)*TBL + e] = pk(bf16(f0), bf16(f1)).
// Halves the per-XCD L2 fill bytes of the gather phase.
// ---------------------------------------------------------------------------
__global__ __launch_bounds__(256) void k_tab16(
    const float* __restrict__ g_tab, unsigned* __restrict__ tab16,
    int n_dense, int n_hashed)
{
    const size_t total_pairs = (size_t)n_hashed * (TBL / 2);   // 2 entries per iter
    const size_t gstride = (size_t)gridDim.x * 256;
    const float* __restrict__ src = g_tab + (size_t)n_dense * (TBL * 2);
    for (size_t i = (size_t)blockIdx.x * 256 + threadIdx.x; i < total_pairs; i += gstride) {
        const f32x4 v = reinterpret_cast<const f32x4*>(src)[i];
        uint2 o;
        o.x = pk(f2bf(v[0]), f2bf(v[1]));
        o.y = pk(f2bf(v[2]), f2bf(v[3]));
        reinterpret_cast<uint2*>(tab16)[i] = o;
    }
}

// ---------------------------------------------------------------------------
// wave dense layer: f32 LDS in, per-k-step RNE hi/lo split (cvt_pk), 3-term
// MFMA (hh + lh + hl), f32 LDS out. In-place on one buffer (proven R7).
// ---------------------------------------------------------------------------
template<int KSTEPS, int NTILES, bool RELU>
__device__ __forceinline__ void wave_layer(float* X,
                                           const unsigned short* __restrict__ wfrag, int cbase,
                                           int wrow, int lane)
{
    f32x4 acc[2][NTILES];
#pragma unroll
    for (int ms = 0; ms < 2; ++ms)
#pragma unroll
        for (int t = 0; t < NTILES; ++t) acc[ms][t] = f32x4{0.f, 0.f, 0.f, 0.f};
    const int r15 = lane & 15, q = lane >> 4;
    const short8* wf8 = reinterpret_cast<const short8*>(wfrag) + (size_t)cbase * 128;
#pragma unroll
    for (int s = 0; s < KSTEPS; ++s) {
        short8 ah[2], al[2];
#pragma unroll
        for (int ms = 0; ms < 2; ++ms) {
            const float* xp = X + (size_t)(wrow + ms * 16 + r15) * LDW + s * 32 + q * 8;
            const f32x4 x0 = reinterpret_cast<const f32x4*>(xp)[0];
            const f32x4 x1 = reinterpret_cast<const f32x4*>(xp)[1];
            union { unsigned u[4]; short8 s8; } uh, ul;
            split_pair(x0[0], x0[1], uh.u[0], ul.u[0]);
            split_pair(x0[2], x0[3], uh.u[1], ul.u[1]);
            split_pair(x1[0], x1[1], uh.u[2], ul.u[2]);
            split_pair(x1[2], x1[3], uh.u[3], ul.u[3]);
            ah[ms] = uh.s8;
            al[ms] = ul.s8;
        }
#pragma unroll
        for (int t = 0; t < NTILES; ++t) {
            const short8* cp = wf8 + (size_t)(s * NTILES + t) * 128;
            const short8 bh = cp[lane];
            const short8 bl = cp[64 + lane];
#pragma unroll
            for (int ms = 0; ms < 2; ++ms) {
                acc[ms][t] = __builtin_amdgcn_mfma_f32_16x16x32_bf16(ah[ms], bh, acc[ms][t], 0, 0, 0);
                acc[ms][t] = __builtin_amdgcn_mfma_f32_16x16x32_bf16(al[ms], bh, acc[ms][t], 0, 0, 0);
                acc[ms][t] = __builtin_amdgcn_mfma_f32_16x16x32_bf16(ah[ms], bl, acc[ms][t], 0, 0, 0);
            }
        }
    }
#pragma unroll
    for (int ms = 0; ms < 2; ++ms)
#pragma unroll
        for (int t = 0; t < NTILES; ++t)
#pragma unroll
            for (int r = 0; r < 4; ++r) {
                float v = acc[ms][t][r];
                if (RELU) v = fmaxf(v, 0.f);
                X[(size_t)(wrow + ms * 16 + q * 4 + r) * LDW + t * 16 + r15] = v;
            }
}

// ---------------------------------------------------------------------------
// Kernel 1: freq encode + warp MLP (MFMA) -> xn planes + DENSE hash levels
// ---------------------------------------------------------------------------
__global__ __launch_bounds__(256, 4) void k_warp_mfma(
    const float* __restrict__ g_pos, const float* __restrict__ g_t,
    const float* __restrict__ g_tab,
    const unsigned short* __restrict__ wfrag,
    float* __restrict__ xn0, float* __restrict__ xn1, float* __restrict__ xn2,
    float* __restrict__ featp, size_t stride, int N, int n_dense, LevelParams lp)
{
    __shared__ float buf[128 * LDW];        // 34.8 KB
    const int tid = threadIdx.x;
    const int base = blockIdx.x * 128;
    const int p = tid & 127;
    const int pn = min(base + p, N - 1);
    const float PI_F = 3.14159265358979323846f;

    {   // enc staging: thread-pairs split the 4 input dims
        const int dpair = tid >> 7;
        float v0, v1;
        if (dpair == 0) { v0 = g_pos[3 * pn + 0]; v1 = g_pos[3 * pn + 1]; }
        else            { v0 = g_pos[3 * pn + 2]; v1 = g_t[pn]; }
#pragma unroll
        for (int e = 0; e < 2; ++e) {
            const float x = e ? v1 : v0;
            const int d = dpair * 2 + e;
            f32x4 sv, cv;
#pragma unroll
            for (int k = 0; k < 4; ++k) {
                const float a = x * (PI_F * (float)(1 << k));
                sv[k] = __sinf(a);
                cv[k] = __cosf(a);
            }
            *reinterpret_cast<f32x4*>(&buf[(size_t)p * LDW + d * 8])     = sv;
            *reinterpret_cast<f32x4*>(&buf[(size_t)p * LDW + d * 8 + 4]) = cv;
        }
    }
    __syncthreads();
    const int lane = tid & 63, wrow = (tid >> 6) * 32;
    wave_layer<1, 4, true >(buf, wfrag, C_W0, wrow, lane);
    wave_layer<2, 4, true >(buf, wfrag, C_W1, wrow, lane);
    wave_layer<2, 1, false>(buf, wfrag, C_W2, wrow, lane);
    __syncthreads();

    // ---- epilogue: xn (both halves compute; half 0 stores) + dense levels
    const int n = base + p;
    const float ox = buf[(size_t)p * LDW + 0];
    const float oy = buf[(size_t)p * LDW + 1];
    const float oz = buf[(size_t)p * LDW + 2];
    const float xnv[3] = { (g_pos[3 * pn + 0] + ox * MOVE_STEP + 1.5f) / 3.0f,
                           (g_pos[3 * pn + 1] + oy * MOVE_STEP + 1.5f) / 3.0f,
                           (g_pos[3 * pn + 2] + oz * MOVE_STEP + 1.5f) / 3.0f };
    if (tid < 128 && n < N) {
        xn0[n] = xnv[0];
        xn1[n] = xnv[1];
        xn2[n] = xnv[2];
    }

    const int dmid = min(3, n_dense);
    const int l0 = (tid < 128) ? 0 : dmid;
    const int l1 = (tid < 128) ? dmid : n_dense;
    for (int l = l0; l < l1; ++l) {
        const float scale = lp.scale[l];
        const int res = lp.res[l];
        float fr[3]; int c0[3];
#pragma unroll
        for (int d = 0; d < 3; ++d) {
            const float pp = xnv[d] * scale + 0.5f;
            const float fl = floorf(pp);
            fr[d] = pp - fl;
            c0[d] = (int)fl;
        }
        const float* __restrict__ tbl = g_tab + (size_t)l * (size_t)(TBL * 2);
        float2 v[8];
#pragma unroll
        for (int c = 0; c < 8; ++c) {
            const int ci = (c >> 2) & 1, cj = (c >> 1) & 1, ck = c & 1;
            const unsigned idx = (unsigned)((c0[0] + ci) + res * ((c0[1] + cj) + res * (c0[2] + ck)));
            v[c] = *reinterpret_cast<const float2*>(tbl + (size_t)idx * 2);
        }
        float f0 = 0.f, f1 = 0.f;
#pragma unroll
        for (int c = 0; c < 8; ++c) {
            const int ci = (c >> 2) & 1, cj = (c >> 1) & 1, ck = c & 1;
            const float w = (ci ? fr[0] : 1.f - fr[0])
                          * (cj ? fr[1] : 1.f - fr[1])
                          * (ck ? fr[2] : 1.f - fr[2]);
            f0 = fmaf(w, v[c].x, f0);
            f1 = fmaf(w, v[c].y, f1);
        }
        if (n < N) {
            __builtin_nontemporal_store(f0, &featp[(size_t)(2 * l)     * stride + n]);
            __builtin_nontemporal_store(f1, &featp[(size_t)(2 * l + 1) * stride + n]);
        }
    }
}

// ---------------------------------------------------------------------------
// Kernel 2 (bf16 tables): all hashed levels, one launch, level = blockIdx.y
// (R9 mapping — blocks of one level dispatch contiguously). One u32 gather
// per corner (4 B) instead of 8 B -> halves L2-fill traffic.
// ---------------------------------------------------------------------------
__global__ __launch_bounds__(HTPB) void k_hash_all16(
    const unsigned* __restrict__ tab16,
    const float* __restrict__ xn0, const float* __restrict__ xn1,
    const float* __restrict__ xn2,
    float* __restrict__ featp, size_t stride, int N, int n_dense, LevelParams lp)
{
    const int l = n_dense + blockIdx.y;
    const float scale = lp.scale[l];
    const unsigned* __restrict__ tbl = tab16 + (size_t)blockIdx.y * TBL;
    float* __restrict__ o0 = featp + (size_t)(2 * l)     * stride;
    float* __restrict__ o1 = featp + (size_t)(2 * l + 1) * stride;

    const int base = blockIdx.x * (HTPB * HPTS) + threadIdx.x;

    int nn[HPTS]; bool av[HPTS];
    float xs[HPTS][3];
#pragma unroll
    for (int k = 0; k < HPTS; ++k) {
        nn[k] = base + k * HTPB;
        av[k] = nn[k] < N;
        const int m = av[k] ? nn[k] : 0;
        xs[k][0] = __builtin_nontemporal_load(&xn0[m]);
        xs[k][1] = __builtin_nontemporal_load(&xn1[m]);
        xs[k][2] = __builtin_nontemporal_load(&xn2[m]);
    }

    float fr[HPTS][3];
    unsigned v[HPTS][8];
#pragma unroll
    for (int k = 0; k < HPTS; ++k) {
        int c0[3];
#pragma unroll
        for (int d = 0; d < 3; ++d) {
            const float pp = xs[k][d] * scale + 0.5f;
            const float fl = floorf(pp);
            fr[k][d] = pp - fl;
            c0[d] = (int)fl;
        }
#pragma unroll
        for (int c = 0; c < 8; ++c) {
            const int ci = (c >> 2) & 1, cj = (c >> 1) & 1, ck = c & 1;
            const unsigned idx = (((unsigned)(c0[0] + ci)) ^ ((unsigned)(c0[1] + cj) * 2654435761u)
                                  ^ ((unsigned)(c0[2] + ck) * 805459861u)) & (TBL - 1u);
            v[k][c] = tbl[idx];
        }
    }

#pragma unroll
    for (int k = 0; k < HPTS; ++k) {
        float f0 = 0.f, f1 = 0.f;
#pragma unroll
        for (int c = 0; c < 8; ++c) {
            const int ci = (c >> 2) & 1, cj = (c >> 1) & 1, ck = c & 1;
            const float w = (ci ? fr[k][0] : 1.f - fr[k][0])
                          * (cj ? fr[k][1] : 1.f - fr[k][1])
                          * (ck ? fr[k][2] : 1.f - fr[k][2]);
            f0 = fmaf(w, bf2f((unsigned short)(v[k][c] & 0xffffu)), f0);
            f1 = fmaf(w, bf2f((unsigned short)(v[k][c] >> 16)), f1);
        }
        if (av[k]) {
            __builtin_nontemporal_store(f0, &o0[nn[k]]);
            __builtin_nontemporal_store(f1, &o1[nn[k]]);
        }
    }
}

// ---------------------------------------------------------------------------
// Kernel 2 fallback (f32 tables, R9-proven) — used only if ws too small
// ---------------------------------------------------------------------------
__global__ __launch_bounds__(HTPB) void k_hash_all(
    const float* __restrict__ g_tab,
    const float* __restrict__ xn0, const float* __restrict__ xn1,
    const float* __restrict__ xn2,
    float* __restrict__ featp, size_t stride, int N, int n_dense, LevelParams lp)
{
    const int l = n_dense + blockIdx.y;
    const float scale = lp.scale[l];
    const float* __restrict__ tbl = g_tab + (size_t)l * (size_t)(TBL * 2);
    float* __restrict__ o0 = featp + (size_t)(2 * l)     * stride;
    float* __restrict__ o1 = featp + (size_t)(2 * l + 1) * stride;

    const int base = blockIdx.x * (HTPB * HPTS) + threadIdx.x;

    int nn[HPTS]; bool av[HPTS];
    float xs[HPTS][3];
#pragma unroll
    for (int k = 0; k < HPTS; ++k) {
        nn[k] = base + k * HTPB;
        av[k] = nn[k] < N;
        const int m = av[k] ? nn[k] : 0;
        xs[k][0] = __builtin_nontemporal_load(&xn0[m]);
        xs[k][1] = __builtin_nontemporal_load(&xn1[m]);
        xs[k][2] = __builtin_nontemporal_load(&xn2[m]);
    }

    float fr[HPTS][3];
    float2 v[HPTS][8];
#pragma unroll
    for (int k = 0; k < HPTS; ++k) {
        int c0[3];
#pragma unroll
        for (int d = 0; d < 3; ++d) {
            const float pp = xs[k][d] * scale + 0.5f;
            const float fl = floorf(pp);
            fr[k][d] = pp - fl;
            c0[d] = (int)fl;
        }
#pragma unroll
        for (int c = 0; c < 8; ++c) {
            const int ci = (c >> 2) & 1, cj = (c >> 1) & 1, ck = c & 1;
            const unsigned idx = (((unsigned)(c0[0] + ci)) ^ ((unsigned)(c0[1] + cj) * 2654435761u)
                                  ^ ((unsigned)(c0[2] + ck) * 805459861u)) & (TBL - 1u);
            v[k][c] = *reinterpret_cast<const float2*>(tbl + (size_t)idx * 2);
        }
    }

#pragma unroll
    for (int k = 0; k < HPTS; ++k) {
        float f0 = 0.f, f1 = 0.f;
#pragma unroll
        for (int c = 0; c < 8; ++c) {
            const int ci = (c >> 2) & 1, cj = (c >> 1) & 1, ck = c & 1;
            const float w = (ci ? fr[k][0] : 1.f - fr[k][0])
                          * (cj ? fr[k][1] : 1.f - fr[k][1])
                          * (ck ? fr[k][2] : 1.f - fr[k][2]);
            f0 = fmaf(w, v[k][c].x, f0);
            f1 = fmaf(w, v[k][c].y, f1);
        }
        if (av[k]) {
            __builtin_nontemporal_store(f0, &o0[nn[k]]);
            __builtin_nontemporal_store(f1, &o1[nn[k]]);
        }
    }
}

// ---------------------------------------------------------------------------
// Kernel 3: base MLP + SH + head MLP (MFMA) -> output
// ---------------------------------------------------------------------------
__global__ __launch_bounds__(256, 4) void k_final_mfma(
    const float* __restrict__ featp, size_t stride,
    const float* __restrict__ xn0, const float* __restrict__ xn1,
    const float* __restrict__ xn2,
    const float* __restrict__ g_dir,
    const unsigned short* __restrict__ wfrag,
    float* __restrict__ g_out, int N)
{
    __shared__ float buf[128 * LDW];        // 34.8 KB
    const int tid = threadIdx.x;
    const int base = blockIdx.x * 128;
    const int p = tid & 127;
    const int pn = min(base + p, N - 1);
    const int fb = (tid >> 7) * 16;

    // stage 32 f32 feat planes -> buf[p][0..31]
#pragma unroll
    for (int j = 0; j < 16; ++j)
        buf[(size_t)p * LDW + fb + j] = featp[(size_t)(fb + j) * stride + pn];
    __syncthreads();

    const int lane = tid & 63, wrow = (tid >> 6) * 32;
    wave_layer<1, 4, true >(buf, wfrag, C_B0, wrow, lane);
    wave_layer<2, 1, false>(buf, wfrag, C_B1, wrow, lane);
    __syncthreads();

    float density = 0.f;
    if (tid < 128) {
        float bb[16];
        const f32x4* bv = reinterpret_cast<const f32x4*>(&buf[(size_t)tid * LDW]);
#pragma unroll
        for (int g4 = 0; g4 < 4; ++g4) {
            const f32x4 v = bv[g4];
#pragma unroll
            for (int j = 0; j < 4; ++j) bb[4 * g4 + j] = v[j];
        }
        const float x0v = xn0[pn], x1v = xn1[pn], x2v = xn2[pn];
        const bool sel = x0v > 0.f && x0v < 1.f && x1v > 0.f && x1v < 1.f &&
                         x2v > 0.f && x2v < 1.f;
        density = sel ? expf(bb[0] - 1.0f) : 0.0f;

        const float ddx = g_dir[3 * pn + 0];
        const float ddy = g_dir[3 * pn + 1];
        const float ddz = g_dir[3 * pn + 2];
        const float nrm = sqrtf(ddx * ddx + ddy * ddy + ddz * ddz);
        const float x = ddx / nrm, y = ddy / nrm, z = ddz / nrm;
        const float xy = x * y, yz = y * z, xz = x * z;
        const float x2 = x * x, y2 = y * y, z2 = z * z;
        f32x4 o0, o1, o2, o3, o4, o5, o6, o7;
        o0[0] = 0.28209479177387814f;
        o0[1] = -0.48860251190291987f * y;
        o0[2] = 0.48860251190291987f * z;
        o0[3] = -0.48860251190291987f * x;
        o1[0] = 1.0925484305920792f * xy;
        o1[1] = -1.0925484305920792f * yz;
        o1[2] = 0.94617469575756f * z2 - 0.31539156525252f;
        o1[3] = -1.0925484305920792f * xz;
        o2[0] = 0.5462742152960396f * (x2 - y2);
        o2[1] = 0.5900435899266435f * y * (y2 - 3.0f * x2);
        o2[2] = 2.890611442640554f * xy * z;
        o2[3] = 0.4570457994644657f * y * (1.0f - 5.0f * z2);
        o3[0] = 0.3731763325901154f * z * (5.0f * z2 - 3.0f);
        o3[1] = 0.4570457994644657f * x * (1.0f - 5.0f * z2);
        o3[2] = 1.445305721320277f * z * (x2 - y2);
        o3[3] = 0.5900435899266435f * x * (3.0f * y2 - x2);
        o4[0] = bb[1];  o4[1] = bb[2];  o4[2] = bb[3];  o4[3] = bb[4];
        o5[0] = bb[5];  o5[1] = bb[6];  o5[2] = bb[7];  o5[3] = bb[8];
        o6[0] = bb[9];  o6[1] = bb[10]; o6[2] = bb[11]; o6[3] = bb[12];
        o7[0] = bb[13]; o7[1] = bb[14]; o7[2] = bb[15]; o7[3] = 0.f;
        f32x4* wb = reinterpret_cast<f32x4*>(&buf[(size_t)tid * LDW]);
        wb[0] = o0; wb[1] = o1; wb[2] = o2; wb[3] = o3;
        wb[4] = o4; wb[5] = o5; wb[6] = o6; wb[7] = o7;
    }
    __syncthreads();

    wave_layer<1, 4, true >(buf, wfrag, C_H0, wrow, lane);
    wave_layer<2, 4, true >(buf, wfrag, C_H1, wrow, lane);
    wave_layer<2, 1, false>(buf, wfrag, C_H2, wrow, lane);
    __syncthreads();

    if (tid < 128 && base + tid < N) {
        const int n = base + tid;
        float4 o;
        o.x = 1.0f / (1.0f + expf(-buf[(size_t)tid * LDW + 0]));
        o.y = 1.0f / (1.0f + expf(-buf[(size_t)tid * LDW + 1]));
        o.z = 1.0f / (1.0f + expf(-buf[(size_t)tid * LDW + 2]));
        o.w = density;
        *reinterpret_cast<float4*>(g_out + (size_t)n * 4) = o;
    }
}

// ---------------------------------------------------------------------------
// Scalar fallback (round-2 monolith) used only if ws too small
// ---------------------------------------------------------------------------
template<int IN, int OUT, bool RELU>
__device__ __forceinline__ void layer(const float* __restrict__ W,
                                      const float* __restrict__ hin,
                                      float* __restrict__ A,
                                      float* __restrict__ out)
{
#pragma unroll
    for (int j = 0; j < OUT; ++j) out[j] = 0.f;
#pragma unroll
    for (int c = 0; c < IN; c += CHUNK) {
#pragma unroll
        for (int i = 0; i < CHUNK; ++i) {
            if (c + i < IN) A[i * TPB] = RELU ? fmaxf(hin[c + i], 0.f) : hin[c + i];
        }
        const int cnt = (IN - c < CHUNK) ? (IN - c) : CHUNK;
#pragma unroll 4
        for (int i = 0; i < cnt; ++i) {
            const float a = A[i * TPB];
            const float* __restrict__ Wr = W + (size_t)(c + i) * OUT;
#pragma unroll
            for (int j = 0; j < OUT; ++j)
                out[j] = fmaf(a, Wr[j], out[j]);
        }
    }
}

__global__ __launch_bounds__(TPB, 4) void dngp_mono(
    const float* __restrict__ g_pos, const float* __restrict__ g_t,
    const float* __restrict__ g_dir, const float* __restrict__ g_tab,
    const float* __restrict__ Ww0, const float* __restrict__ Ww1, const float* __restrict__ Ww2,
    const float* __restrict__ Wb0, const float* __restrict__ Wb1,
    const float* __restrict__ Wh0, const float* __restrict__ Wh1, const float* __restrict__ Wh2,
    float* __restrict__ g_out, int N, LevelParams lp)
{
    __shared__ float s_act[CHUNK * TPB];
    const int tid = threadIdx.x;
    const int n = blockIdx.x * TPB + tid;
    if (n >= N) return;
    float* __restrict__ A = s_act + tid;

    const float px = g_pos[3 * n + 0];
    const float py = g_pos[3 * n + 1];
    const float pz = g_pos[3 * n + 2];
    const float tt = g_t[n];

    float enc[32];
    {
        const float xin[4] = { px, py, pz, tt };
        const float PI_F = 3.14159265358979323846f;
#pragma unroll
        for (int d = 0; d < 4; ++d)
#pragma unroll
            for (int k = 0; k < 4; ++k) {
                float s, c;
                sincosf(xin[d] * (PI_F * (float)(1 << k)), &s, &c);
                enc[d * 8 + k]     = s;
                enc[d * 8 + 4 + k] = c;
            }
    }

    float h[64], h2[64], off[3];
    layer<32, 64, false>(Ww0, enc, A, h);
    layer<64, 64, true >(Ww1, h,   A, h2);
    layer<64, 3,  true >(Ww2, h2,  A, off);

    const float xn[3] = { (px + off[0] * MOVE_STEP + 1.5f) / 3.0f,
                          (py + off[1] * MOVE_STEP + 1.5f) / 3.0f,
                          (pz + off[2] * MOVE_STEP + 1.5f) / 3.0f };
    const bool sel = xn[0] > 0.f && xn[0] < 1.f && xn[1] > 0.f && xn[1] < 1.f &&
                     xn[2] > 0.f && xn[2] < 1.f;

    float feat[32];
#pragma unroll 2
    for (int l = 0; l < N_LVL; ++l) {
        const float scale = lp.scale[l];
        const int res = lp.res[l];
        float fr[3]; int c0[3];
#pragma unroll
        for (int d = 0; d < 3; ++d) {
            const float pp = xn[d] * scale + 0.5f;
            const float fl = floorf(pp);
            fr[d] = pp - fl;
            c0[d] = (int)fl;
        }
        const float* __restrict__ tbl = g_tab + (size_t)l * (size_t)(TBL * 2);
        float f0 = 0.f, f1 = 0.f;
        if (lp.dense[l]) {
#pragma unroll
            for (int c = 0; c < 8; ++c) {
                const int ci = (c >> 2) & 1, cj = (c >> 1) & 1, ck = c & 1;
                const unsigned idx = (unsigned)((c0[0] + ci) + res * ((c0[1] + cj) + res * (c0[2] + ck)));
                const float2 f = *reinterpret_cast<const float2*>(tbl + (size_t)idx * 2);
                const float w = (ci ? fr[0] : 1.f - fr[0]) * (cj ? fr[1] : 1.f - fr[1]) * (ck ? fr[2] : 1.f - fr[2]);
                f0 = fmaf(w, f.x, f0);
                f1 = fmaf(w, f.y, f1);
            }
        } else {
#pragma unroll
            for (int c = 0; c < 8; ++c) {
                const int ci = (c >> 2) & 1, cj = (c >> 1) & 1, ck = c & 1;
                const unsigned hx = (unsigned)(c0[0] + ci);
                const unsigned hy = (unsigned)(c0[1] + cj) * 2654435761u;
                const unsigned hz = (unsigned)(c0[2] + ck) * 805459861u;
                const unsigned idx = (hx ^ hy ^ hz) & (TBL - 1u);
                const float2 f = *reinterpret_cast<const float2*>(tbl + (size_t)idx * 2);
                const float w = (ci ? fr[0] : 1.f - fr[0]) * (cj ? fr[1] : 1.f - fr[1]) * (ck ? fr[2] : 1.f - fr[2]);
                f0 = fmaf(w, f.x, f0);
                f1 = fmaf(w, f.y, f1);
            }
        }
        feat[2 * l]     = f0;
        feat[2 * l + 1] = f1;
    }

    layer<32, 64, false>(Wb0, feat, A, h);
    float b[16];
    layer<64, 16, true >(Wb1, h, A, b);
    const float density = sel ? expf(b[0] - 1.0f) : 0.0f;

    float hin[31];
    {
        const float ddx = g_dir[3 * n + 0];
        const float ddy = g_dir[3 * n + 1];
        const float ddz = g_dir[3 * n + 2];
        const float nrm = sqrtf(ddx * ddx + ddy * ddy + ddz * ddz);
        const float x = ddx / nrm, y = ddy / nrm, z = ddz / nrm;
        const float xy = x * y, yz = y * z, xz = x * z;
        const float x2_ = x * x, y2 = y * y, z2 = z * z;
        hin[0]  = 0.28209479177387814f;
        hin[1]  = -0.48860251190291987f * y;
        hin[2]  = 0.48860251190291987f * z;
        hin[3]  = -0.48860251190291987f * x;
        hin[4]  = 1.0925484305920792f * xy;
        hin[5]  = -1.0925484305920792f * yz;
        hin[6]  = 0.94617469575756f * z2 - 0.31539156525252f;
        hin[7]  = -1.0925484305920792f * xz;
        hin[8]  = 0.5462742152960396f * (x2_ - y2);
        hin[9]  = 0.5900435899266435f * y * (y2 - 3.0f * x2_);
        hin[10] = 2.890611442640554f * xy * z;
        hin[11] = 0.4570457994644657f * y * (1.0f - 5.0f * z2);
        hin[12] = 0.3731763325901154f * z * (5.0f * z2 - 3.0f);
        hin[13] = 0.4570457994644657f * x * (1.0f - 5.0f * z2);
        hin[14] = 1.445305721320277f * z * (x2_ - y2);
        hin[15] = 0.5900435899266435f * x * (3.0f * y2 - x2_);
#pragma unroll
        for (int j = 0; j < 15; ++j) hin[16 + j] = b[1 + j];
    }

    layer<31, 64, false>(Wh0, hin, A, h);
    layer<64, 64, true >(Wh1, h,   A, h2);
    float rgb[3];
    layer<64, 3,  true >(Wh2, h2,  A, rgb);

    float4 o;
    o.x = 1.0f / (1.0f + expf(-rgb[0]));
    o.y = 1.0f / (1.0f + expf(-rgb[1]));
    o.z = 1.0f / (1.0f + expf(-rgb[2]));
    o.w = density;
    *reinterpret_cast<float4*>(g_out + (size_t)n * 4) = o;
}

extern "C" void kernel_launch(void* const* d_in, const int* in_sizes, int n_in,
                              void* d_out, int out_size, void* d_ws, size_t ws_size,
                              hipStream_t stream)
{
    const float* g_pos = (const float*)d_in[0];
    const float* g_t   = (const float*)d_in[1];
    const float* g_dir = (const float*)d_in[2];
    const float* g_tab = (const float*)d_in[3];
    const float* Ww0   = (const float*)d_in[4];
    const float* Ww1   = (const float*)d_in[5];
    const float* Ww2   = (const float*)d_in[6];
    const float* Wb0   = (const float*)d_in[7];
    const float* Wb1   = (const float*)d_in[8];
    const float* Wh0   = (const float*)d_in[9];
    const float* Wh1   = (const float*)d_in[10];
    const float* Wh2   = (const float*)d_in[11];
    const int N = in_sizes[0] / 3;

    LevelParams lp;
    int n_dense = 0;
    const double Bv = exp(log(4096.0 / 16.0) / 15.0);
    for (int l = 0; l < N_LVL; ++l) {
        const double s = 16.0 * pow(Bv, (double)l) - 1.0;
        lp.scale[l] = (float)s;
        const int r = (int)ceil(s) + 1;
        lp.res[l] = r;
        lp.dense[l] = ((long long)r * r * r <= (long long)TBL) ? 1 : 0;
        if (lp.dense[l]) n_dense = l + 1;
    }
    const int n_hashed = N_LVL - n_dense;

    const size_t stride = ((size_t)N + 259) & ~(size_t)3;
    const size_t base_need  = (size_t)C_TOT * 2048 + stride * 4 * (3 + 32);
    const size_t tab16_need = (size_t)n_hashed * TBL * 4;

    if (ws_size >= base_need) {
        unsigned short* wfrag = (unsigned short*)d_ws;
        float* xn0 = (float*)((char*)d_ws + (size_t)C_TOT * 2048);
        float* xn1 = xn0 + stride;
        float* xn2 = xn1 + stride;
        float* featp = xn2 + stride;                          // 32 f32 planes
        unsigned* tab16 = (unsigned*)(featp + 32 * stride);

        AllLayers al;
        al.L[0] = { Ww0, 32, 64, 1, 4, C_W0 };
        al.L[1] = { Ww1, 64, 64, 2, 4, C_W1 };
        al.L[2] = { Ww2, 64,  3, 2, 1, C_W2 };
        al.L[3] = { Wb0, 32, 64, 1, 4, C_B0 };
        al.L[4] = { Wb1, 64, 16, 2, 1, C_B1 };
        al.L[5] = { Wh0, 31, 64, 1, 4, C_H0 };
        al.L[6] = { Wh1, 64, 64, 2, 4, C_H1 };
        al.L[7] = { Wh2, 64,  3, 2, 1, C_H2 };

        const int nchunk = (N + HTPB * HPTS - 1) / (HTPB * HPTS);
        const bool use16 = (ws_size >= base_need + tab16_need);

        dim3 mgrid((N + 127) / 128), mblock(256);
        dim3 hgrid(nchunk, n_hashed), hblock(HTPB);

        hipLaunchKernelGGL(k_prep, dim3(8), dim3(256), 0, stream, al, wfrag);
        if (use16) {
            hipLaunchKernelGGL(k_tab16, dim3(2048), dim3(256), 0, stream,
                               g_tab, tab16, n_dense, n_hashed);
        }

        hipLaunchKernelGGL(k_warp_mfma, mgrid, mblock, 0, stream,
                           g_pos, g_t, g_tab, wfrag, xn0, xn1, xn2,
                           featp, stride, N, n_dense, lp);

        if (use16) {
            hipLaunchKernelGGL(k_hash_all16, hgrid, hblock, 0, stream,
                               tab16, xn0, xn1, xn2, featp, stride, N, n_dense, lp);
        } else {
            hipLaunchKernelGGL(k_hash_all, hgrid, hblock, 0, stream,
                               g_tab, xn0, xn1, xn2, featp, stride, N, n_dense, lp);
        }

        hipLaunchKernelGGL(k_final_mfma, mgrid, mblock, 0, stream,
                           featp, stride, xn0, xn1, xn2, g_dir,
                           wfrag, (float*)d_out, N);
    } else {
        dim3 grid((N + TPB - 1) / TPB), block(TPB);
        hipLaunchKernelGGL(dngp_mono, grid, block, 0, stream,
                           g_pos, g_t, g_dir, g_tab,
                           Ww0, Ww1, Ww2, Wb0, Wb1, Wh0, Wh1, Wh2,
                           (float*)d_out, N, lp);
    }
}

// Round 12
// 276.867 us; speedup vs baseline: 1.4865x; 1.1144x over previous
//
#include <hip/hip_runtime.h>
#include <math.h>

#define TPB   128     // scalar fallback
#define HTPB  256
#define HPTS  4       // points per thread in hash kernel
#define CHUNK 32
#define LDW   68      // f32 LDS row stride: 272 B, 16B-aligned
constexpr int  N_LVL = 16;
constexpr unsigned TBL = 1u << 19;
constexpr float MOVE_STEP = 1.0f / 4096.0f;

typedef __attribute__((ext_vector_type(8))) short short8;
typedef __attribute__((ext_vector_type(4))) float f32x4;

struct LevelParams { float scale[N_LVL]; int res[N_LVL]; int dense[N_LVL]; };

// weight-fragment chunks (2048 B each = hi[64 lanes][short8] + lo[...])
enum { C_W0 = 0, C_W1 = 4, C_W2 = 12, C_B0 = 14, C_B1 = 18, C_H0 = 20, C_H1 = 24, C_H2 = 32, C_TOT = 34 };

struct LayerDesc { const float* W; int K; int N; int ksteps; int ntiles; int cbase; };
struct AllLayers { LayerDesc L[8]; };

__device__ __forceinline__ unsigned short f2bf(float x) {
    unsigned int u = __float_as_uint(x);
    u += 0x7FFFu + ((u >> 16) & 1u);            // RNE
    return (unsigned short)(u >> 16);
}
__device__ __forceinline__ float bf2f(unsigned short h) {
    return __uint_as_float(((unsigned int)h) << 16);
}
__device__ __forceinline__ unsigned pk(unsigned short a, unsigned short b) {
    return (unsigned)a | ((unsigned)b << 16);
}

// hw RNE pack: bf16(a) in [15:0], bf16(b) in [31:16]
__device__ __forceinline__ unsigned cvt_pk_bf16(float a, float b) {
    unsigned r;
    asm("v_cvt_pk_bf16_f32 %0, %1, %2" : "=v"(r) : "v"(a), "v"(b));
    return r;
}
// RNE hi/lo split of a float pair via cvt_pk. Same RNE as f2bf; residual exact.
__device__ __forceinline__ void split_pair(float a, float b, unsigned& hp, unsigned& lp) {
    hp = cvt_pk_bf16(a, b);
    const float ha = __uint_as_float(hp << 16);
    const float hb = __uint_as_float(hp & 0xffff0000u);
    lp = cvt_pk_bf16(a - ha, b - hb);
}

// ---------------------------------------------------------------------------
// prep: split weights into bf16 (hi,lo) MFMA B-fragments (RNE), per-lane order
// ---------------------------------------------------------------------------
__global__ __launch_bounds__(256) void k_prep(AllLayers al, unsigned short* __restrict__ wfrag)
{
    const LayerDesc d = al.L[blockIdx.x];
    const int total = d.ksteps * d.ntiles * 64;
    for (int slot = threadIdx.x; slot < total; slot += 256) {
        const int lane = slot & 63;
        const int c = slot >> 6;
        const int s = c / d.ntiles;
        const int t = c - s * d.ntiles;
        short8 hv, lv;
#pragma unroll
        for (int j = 0; j < 8; ++j) {
            const int k = s * 32 + ((lane >> 4) << 3) + j;
            const int n = t * 16 + (lane & 15);
            const float w = (k < d.K && n < d.N) ? d.W[k * d.N + n] : 0.f;
            const unsigned short hi = f2bf(w);
            const unsigned short lo = f2bf(w - bf2f(hi));
            hv[j] = (short)hi;
            lv[j] = (short)lo;
        }
        short8* b8 = reinterpret_cast<short8*>(wfrag + (size_t)(d.cbase + c) * 1024);
        b8[lane]      = hv;
        b8[64 + lane] = lv;
    }
}

// ---------------------------------------------------------------------------
// prep 2: convert hashed-level tables to packed bf16x2 (4 B/entry)
// ---------------------------------------------------------------------------
__global__ __launch_bounds__(256) void k_tab16(
    const float* __restrict__ g_tab, unsigned* __restrict__ tab16,
    int n_dense, int n_hashed)
{
    const size_t total_pairs = (size_t)n_hashed * (TBL / 2);
    const size_t gstride = (size_t)gridDim.x * 256;
    const float* __restrict__ src = g_tab + (size_t)n_dense * (TBL * 2);
    for (size_t i = (size_t)blockIdx.x * 256 + threadIdx.x; i < total_pairs; i += gstride) {
        const f32x4 v = reinterpret_cast<const f32x4*>(src)[i];
        uint2 o;
        o.x = pk(f2bf(v[0]), f2bf(v[1]));
        o.y = pk(f2bf(v[2]), f2bf(v[3]));
        reinterpret_cast<uint2*>(tab16)[i] = o;
    }
}

// ---------------------------------------------------------------------------
// wave dense layer: f32 LDS in, per-k-step RNE hi/lo split (cvt_pk), 3-term
// MFMA (hh + lh + hl), f32 LDS out. In-place on one buffer (proven R7).
// ---------------------------------------------------------------------------
template<int KSTEPS, int NTILES, bool RELU>
__device__ __forceinline__ void wave_layer(float* X,
                                           const unsigned short* __restrict__ wfrag, int cbase,
                                           int wrow, int lane)
{
    f32x4 acc[2][NTILES];
#pragma unroll
    for (int ms = 0; ms < 2; ++ms)
#pragma unroll
        for (int t = 0; t < NTILES; ++t) acc[ms][t] = f32x4{0.f, 0.f, 0.f, 0.f};
    const int r15 = lane & 15, q = lane >> 4;
    const short8* wf8 = reinterpret_cast<const short8*>(wfrag) + (size_t)cbase * 128;
#pragma unroll
    for (int s = 0; s < KSTEPS; ++s) {
        short8 ah[2], al[2];
#pragma unroll
        for (int ms = 0; ms < 2; ++ms) {
            const float* xp = X + (size_t)(wrow + ms * 16 + r15) * LDW + s * 32 + q * 8;
            const f32x4 x0 = reinterpret_cast<const f32x4*>(xp)[0];
            const f32x4 x1 = reinterpret_cast<const f32x4*>(xp)[1];
            union { unsigned u[4]; short8 s8; } uh, ul;
            split_pair(x0[0], x0[1], uh.u[0], ul.u[0]);
            split_pair(x0[2], x0[3], uh.u[1], ul.u[1]);
            split_pair(x1[0], x1[1], uh.u[2], ul.u[2]);
            split_pair(x1[2], x1[3], uh.u[3], ul.u[3]);
            ah[ms] = uh.s8;
            al[ms] = ul.s8;
        }
#pragma unroll
        for (int t = 0; t < NTILES; ++t) {
            const short8* cp = wf8 + (size_t)(s * NTILES + t) * 128;
            const short8 bh = cp[lane];
            const short8 bl = cp[64 + lane];
#pragma unroll
            for (int ms = 0; ms < 2; ++ms) {
                acc[ms][t] = __builtin_amdgcn_mfma_f32_16x16x32_bf16(ah[ms], bh, acc[ms][t], 0, 0, 0);
                acc[ms][t] = __builtin_amdgcn_mfma_f32_16x16x32_bf16(al[ms], bh, acc[ms][t], 0, 0, 0);
                acc[ms][t] = __builtin_amdgcn_mfma_f32_16x16x32_bf16(ah[ms], bl, acc[ms][t], 0, 0, 0);
            }
        }
    }
#pragma unroll
    for (int ms = 0; ms < 2; ++ms)
#pragma unroll
        for (int t = 0; t < NTILES; ++t)
#pragma unroll
            for (int r = 0; r < 4; ++r) {
                float v = acc[ms][t][r];
                if (RELU) v = fmaxf(v, 0.f);
                X[(size_t)(wrow + ms * 16 + q * 4 + r) * LDW + t * 16 + r15] = v;
            }
}

// ---------------------------------------------------------------------------
// Kernel 1: freq encode + warp MLP (MFMA) -> xn4 plane + DENSE hash levels
// (dense feats packed bf16x2 into featp planes 0..n_dense-1)
// ---------------------------------------------------------------------------
__global__ __launch_bounds__(256, 4) void k_warp_mfma(
    const float* __restrict__ g_pos, const float* __restrict__ g_t,
    const float* __restrict__ g_tab,
    const unsigned short* __restrict__ wfrag,
    float* __restrict__ xn4,
    unsigned* __restrict__ featp, size_t stride, int N, int n_dense, LevelParams lp)
{
    __shared__ float buf[128 * LDW];        // 34.8 KB
    const int tid = threadIdx.x;
    const int base = blockIdx.x * 128;
    const int p = tid & 127;
    const int pn = min(base + p, N - 1);
    const float PI_F = 3.14159265358979323846f;

    {   // enc staging: thread-pairs split the 4 input dims
        const int dpair = tid >> 7;
        float v0, v1;
        if (dpair == 0) { v0 = g_pos[3 * pn + 0]; v1 = g_pos[3 * pn + 1]; }
        else            { v0 = g_pos[3 * pn + 2]; v1 = g_t[pn]; }
#pragma unroll
        for (int e = 0; e < 2; ++e) {
            const float x = e ? v1 : v0;
            const int d = dpair * 2 + e;
            f32x4 sv, cv;
#pragma unroll
            for (int k = 0; k < 4; ++k) {
                const float a = x * (PI_F * (float)(1 << k));
                sv[k] = __sinf(a);
                cv[k] = __cosf(a);
            }
            *reinterpret_cast<f32x4*>(&buf[(size_t)p * LDW + d * 8])     = sv;
            *reinterpret_cast<f32x4*>(&buf[(size_t)p * LDW + d * 8 + 4]) = cv;
        }
    }
    __syncthreads();
    const int lane = tid & 63, wrow = (tid >> 6) * 32;
    wave_layer<1, 4, true >(buf, wfrag, C_W0, wrow, lane);
    wave_layer<2, 4, true >(buf, wfrag, C_W1, wrow, lane);
    wave_layer<2, 1, false>(buf, wfrag, C_W2, wrow, lane);
    __syncthreads();

    // ---- epilogue: xn4 (half 0 stores) + dense levels (packed bf16 feat)
    const int n = base + p;
    const float ox = buf[(size_t)p * LDW + 0];
    const float oy = buf[(size_t)p * LDW + 1];
    const float oz = buf[(size_t)p * LDW + 2];
    const float xnv[3] = { (g_pos[3 * pn + 0] + ox * MOVE_STEP + 1.5f) / 3.0f,
                           (g_pos[3 * pn + 1] + oy * MOVE_STEP + 1.5f) / 3.0f,
                           (g_pos[3 * pn + 2] + oz * MOVE_STEP + 1.5f) / 3.0f };
    if (tid < 128 && n < N) {
        reinterpret_cast<f32x4*>(xn4)[n] = f32x4{ xnv[0], xnv[1], xnv[2], 0.f };
    }

    const int dmid = min(3, n_dense);
    const int l0 = (tid < 128) ? 0 : dmid;
    const int l1 = (tid < 128) ? dmid : n_dense;
    for (int l = l0; l < l1; ++l) {
        const float scale = lp.scale[l];
        const int res = lp.res[l];
        float fr[3]; int c0[3];
#pragma unroll
        for (int d = 0; d < 3; ++d) {
            const float pp = xnv[d] * scale + 0.5f;
            const float fl = floorf(pp);
            fr[d] = pp - fl;
            c0[d] = (int)fl;
        }
        const float* __restrict__ tbl = g_tab + (size_t)l * (size_t)(TBL * 2);
        float2 v[8];
#pragma unroll
        for (int c = 0; c < 8; ++c) {
            const int ci = (c >> 2) & 1, cj = (c >> 1) & 1, ck = c & 1;
            const unsigned idx = (unsigned)((c0[0] + ci) + res * ((c0[1] + cj) + res * (c0[2] + ck)));
            v[c] = *reinterpret_cast<const float2*>(tbl + (size_t)idx * 2);
        }
        float f0 = 0.f, f1 = 0.f;
#pragma unroll
        for (int c = 0; c < 8; ++c) {
            const int ci = (c >> 2) & 1, cj = (c >> 1) & 1, ck = c & 1;
            const float w = (ci ? fr[0] : 1.f - fr[0])
                          * (cj ? fr[1] : 1.f - fr[1])
                          * (ck ? fr[2] : 1.f - fr[2]);
            f0 = fmaf(w, v[c].x, f0);
            f1 = fmaf(w, v[c].y, f1);
        }
        if (n < N) {
            __builtin_nontemporal_store(pk(f2bf(f0), f2bf(f1)), &featp[(size_t)l * stride + n]);
        }
    }
}

// ---------------------------------------------------------------------------
// Kernel 2 (bf16 tables): all hashed levels, level = blockIdx.y.
// Request-count reductions (values identical):
//  - xn as one float4 load (was 3 loads)
//  - x-corner pairs: u64 at (idxA & ~1) always contains corner A; for even x
//    corner B is the other half (idxB = idxA^1). Odd-x points issue 4 extra
//    predicated u32 loads. 8 -> 6 avg gathers/point/level.
//  - packed bf16x2 feat store (was 2 stores)
// ---------------------------------------------------------------------------
__global__ __launch_bounds__(HTPB) void k_hash_all16(
    const unsigned* __restrict__ tab16,
    const float* __restrict__ xn4,
    unsigned* __restrict__ featp, size_t stride, int N, int n_dense, LevelParams lp)
{
    const int l = n_dense + blockIdx.y;
    const float scale = lp.scale[l];
    const unsigned* __restrict__ tbl = tab16 + (size_t)blockIdx.y * TBL;
    unsigned* __restrict__ op = featp + (size_t)l * stride;

    const int base = blockIdx.x * (HTPB * HPTS) + threadIdx.x;

    int nn[HPTS]; bool av[HPTS];
    f32x4 xs[HPTS];
#pragma unroll
    for (int k = 0; k < HPTS; ++k) {
        nn[k] = base + k * HTPB;
        av[k] = nn[k] < N;
        const int m = av[k] ? nn[k] : 0;
        xs[k] = reinterpret_cast<const f32x4*>(xn4)[m];
    }

    float frx[HPTS];
    float wyz[HPTS][4];
    uint2 w2[HPTS][4];
    unsigned vodd[HPTS][4] = {};
    unsigned ahi[HPTS];      // bit pc: iA&1
    bool oddx[HPTS];
#pragma unroll
    for (int k = 0; k < HPTS; ++k) {
        int c0[3]; float fr[3];
#pragma unroll
        for (int d = 0; d < 3; ++d) {
            const float pp = xs[k][d] * scale + 0.5f;
            const float fl = floorf(pp);
            fr[d] = pp - fl;
            c0[d] = (int)fl;
        }
        frx[k] = fr[0];
        const unsigned ux  = (unsigned)c0[0];
        const unsigned ry0 = (unsigned)c0[1] * 2654435761u;
        const unsigned ry1 = (unsigned)(c0[1] + 1) * 2654435761u;
        const unsigned rz0 = (unsigned)c0[2] * 805459861u;
        const unsigned rz1 = (unsigned)(c0[2] + 1) * 805459861u;
        oddx[k] = (c0[0] & 1) != 0;
        const float wy0 = 1.f - fr[1], wy1 = fr[1];
        const float wz0 = 1.f - fr[2], wz1 = fr[2];
        wyz[k][0] = wy0 * wz0; wyz[k][1] = wy0 * wz1;
        wyz[k][2] = wy1 * wz0; wyz[k][3] = wy1 * wz1;
        const unsigned rr[4] = { ry0 ^ rz0, ry0 ^ rz1, ry1 ^ rz0, ry1 ^ rz1 };
        unsigned hb = 0;
#pragma unroll
        for (int pc = 0; pc < 4; ++pc) {
            const unsigned iA = (ux ^ rr[pc]) & (TBL - 1u);
            hb |= (iA & 1u) << pc;
            w2[k][pc] = *reinterpret_cast<const uint2*>(tbl + (iA & ~1u));
        }
        ahi[k] = hb;
        if (oddx[k]) {
#pragma unroll
            for (int pc = 0; pc < 4; ++pc) {
                const unsigned iB = ((ux + 1u) ^ rr[pc]) & (TBL - 1u);
                vodd[k][pc] = tbl[iB];
            }
        }
    }

#pragma unroll
    for (int k = 0; k < HPTS; ++k) {
        float f0 = 0.f, f1 = 0.f;
        const float wx0 = 1.f - frx[k], wx1 = frx[k];
#pragma unroll
        for (int pc = 0; pc < 4; ++pc) {
            const unsigned lo = w2[k][pc].x, hi = w2[k][pc].y;
            const bool a_hi = ((ahi[k] >> pc) & 1u) != 0;
            const unsigned vA = a_hi ? hi : lo;
            const unsigned vB = oddx[k] ? vodd[k][pc] : (a_hi ? lo : hi);
            const float wA = wx0 * wyz[k][pc];
            const float wB = wx1 * wyz[k][pc];
            f0 = fmaf(wA, bf2f((unsigned short)(vA & 0xffffu)), f0);
            f1 = fmaf(wA, bf2f((unsigned short)(vA >> 16)), f1);
            f0 = fmaf(wB, bf2f((unsigned short)(vB & 0xffffu)), f0);
            f1 = fmaf(wB, bf2f((unsigned short)(vB >> 16)), f1);
        }
        if (av[k]) __builtin_nontemporal_store(pk(f2bf(f0), f2bf(f1)), &op[nn[k]]);
    }
}

// ---------------------------------------------------------------------------
// Kernel 3: base MLP + SH + head MLP (MFMA) -> output
// ---------------------------------------------------------------------------
__global__ __launch_bounds__(256, 4) void k_final_mfma(
    const unsigned* __restrict__ featp, size_t stride,
    const float* __restrict__ xn4,
    const float* __restrict__ g_dir,
    const unsigned short* __restrict__ wfrag,
    float* __restrict__ g_out, int N)
{
    __shared__ float buf[128 * LDW];        // 34.8 KB
    const int tid = threadIdx.x;
    const int base = blockIdx.x * 128;
    const int p = tid & 127;
    const int pn = min(base + p, N - 1);
    const int g = tid >> 7;

    // stage 16 packed feat planes -> buf[p][0..31] (unpack bf16 -> f32)
#pragma unroll
    for (int j = 0; j < 8; ++j) {
        const int l = g * 8 + j;
        const unsigned v = __builtin_nontemporal_load(&featp[(size_t)l * stride + pn]);
        buf[(size_t)p * LDW + 2 * l]     = bf2f((unsigned short)(v & 0xffffu));
        buf[(size_t)p * LDW + 2 * l + 1] = bf2f((unsigned short)(v >> 16));
    }
    __syncthreads();

    const int lane = tid & 63, wrow = (tid >> 6) * 32;
    wave_layer<1, 4, true >(buf, wfrag, C_B0, wrow, lane);
    wave_layer<2, 1, false>(buf, wfrag, C_B1, wrow, lane);
    __syncthreads();

    float density = 0.f;
    if (tid < 128) {
        float bb[16];
        const f32x4* bv = reinterpret_cast<const f32x4*>(&buf[(size_t)tid * LDW]);
#pragma unroll
        for (int g4 = 0; g4 < 4; ++g4) {
            const f32x4 v = bv[g4];
#pragma unroll
            for (int j = 0; j < 4; ++j) bb[4 * g4 + j] = v[j];
        }
        const f32x4 xv = reinterpret_cast<const f32x4*>(xn4)[pn];
        const bool sel = xv[0] > 0.f && xv[0] < 1.f && xv[1] > 0.f && xv[1] < 1.f &&
                         xv[2] > 0.f && xv[2] < 1.f;
        density = sel ? expf(bb[0] - 1.0f) : 0.0f;

        const float ddx = g_dir[3 * pn + 0];
        const float ddy = g_dir[3 * pn + 1];
        const float ddz = g_dir[3 * pn + 2];
        const float nrm = sqrtf(ddx * ddx + ddy * ddy + ddz * ddz);
        const float x = ddx / nrm, y = ddy / nrm, z = ddz / nrm;
        const float xy = x * y, yz = y * z, xz = x * z;
        const float x2 = x * x, y2 = y * y, z2 = z * z;
        f32x4 o0, o1, o2, o3, o4, o5, o6, o7;
        o0[0] = 0.28209479177387814f;
        o0[1] = -0.48860251190291987f * y;
        o0[2] = 0.48860251190291987f * z;
        o0[3] = -0.48860251190291987f * x;
        o1[0] = 1.0925484305920792f * xy;
        o1[1] = -1.0925484305920792f * yz;
        o1[2] = 0.94617469575756f * z2 - 0.31539156525252f;
        o1[3] = -1.0925484305920792f * xz;
        o2[0] = 0.5462742152960396f * (x2 - y2);
        o2[1] = 0.5900435899266435f * y * (y2 - 3.0f * x2);
        o2[2] = 2.890611442640554f * xy * z;
        o2[3] = 0.4570457994644657f * y * (1.0f - 5.0f * z2);
        o3[0] = 0.3731763325901154f * z * (5.0f * z2 - 3.0f);
        o3[1] = 0.4570457994644657f * x * (1.0f - 5.0f * z2);
        o3[2] = 1.445305721320277f * z * (x2 - y2);
        o3[3] = 0.5900435899266435f * x * (3.0f * y2 - x2);
        o4[0] = bb[1];  o4[1] = bb[2];  o4[2] = bb[3];  o4[3] = bb[4];
        o5[0] = bb[5];  o5[1] = bb[6];  o5[2] = bb[7];  o5[3] = bb[8];
        o6[0] = bb[9];  o6[1] = bb[10]; o6[2] = bb[11]; o6[3] = bb[12];
        o7[0] = bb[13]; o7[1] = bb[14]; o7[2] = bb[15]; o7[3] = 0.f;
        f32x4* wb = reinterpret_cast<f32x4*>(&buf[(size_t)tid * LDW]);
        wb[0] = o0; wb[1] = o1; wb[2] = o2; wb[3] = o3;
        wb[4] = o4; wb[5] = o5; wb[6] = o6; wb[7] = o7;
    }
    __syncthreads();

    wave_layer<1, 4, true >(buf, wfrag, C_H0, wrow, lane);
    wave_layer<2, 4, true >(buf, wfrag, C_H1, wrow, lane);
    wave_layer<2, 1, false>(buf, wfrag, C_H2, wrow, lane);
    __syncthreads();

    if (tid < 128 && base + tid < N) {
        const int n = base + tid;
        float4 o;
        o.x = 1.0f / (1.0f + expf(-buf[(size_t)tid * LDW + 0]));
        o.y = 1.0f / (1.0f + expf(-buf[(size_t)tid * LDW + 1]));
        o.z = 1.0f / (1.0f + expf(-buf[(size_t)tid * LDW + 2]));
        o.w = density;
        *reinterpret_cast<float4*>(g_out + (size_t)n * 4) = o;
    }
}

// ---------------------------------------------------------------------------
// Scalar fallback (round-2 monolith) used only if ws too small
// ---------------------------------------------------------------------------
template<int IN, int OUT, bool RELU>
__device__ __forceinline__ void layer(const float* __restrict__ W,
                                      const float* __restrict__ hin,
                                      float* __restrict__ A,
                                      float* __restrict__ out)
{
#pragma unroll
    for (int j = 0; j < OUT; ++j) out[j] = 0.f;
#pragma unroll
    for (int c = 0; c < IN; c += CHUNK) {
#pragma unroll
        for (int i = 0; i < CHUNK; ++i) {
            if (c + i < IN) A[i * TPB] = RELU ? fmaxf(hin[c + i], 0.f) : hin[c + i];
        }
        const int cnt = (IN - c < CHUNK) ? (IN - c) : CHUNK;
#pragma unroll 4
        for (int i = 0; i < cnt; ++i) {
            const float a = A[i * TPB];
            const float* __restrict__ Wr = W + (size_t)(c + i) * OUT;
#pragma unroll
            for (int j = 0; j < OUT; ++j)
                out[j] = fmaf(a, Wr[j], out[j]);
        }
    }
}

__global__ __launch_bounds__(TPB, 4) void dngp_mono(
    const float* __restrict__ g_pos, const float* __restrict__ g_t,
    const float* __restrict__ g_dir, const float* __restrict__ g_tab,
    const float* __restrict__ Ww0, const float* __restrict__ Ww1, const float* __restrict__ Ww2,
    const float* __restrict__ Wb0, const float* __restrict__ Wb1,
    const float* __restrict__ Wh0, const float* __restrict__ Wh1, const float* __restrict__ Wh2,
    float* __restrict__ g_out, int N, LevelParams lp)
{
    __shared__ float s_act[CHUNK * TPB];
    const int tid = threadIdx.x;
    const int n = blockIdx.x * TPB + tid;
    if (n >= N) return;
    float* __restrict__ A = s_act + tid;

    const float px = g_pos[3 * n + 0];
    const float py = g_pos[3 * n + 1];
    const float pz = g_pos[3 * n + 2];
    const float tt = g_t[n];

    float enc[32];
    {
        const float xin[4] = { px, py, pz, tt };
        const float PI_F = 3.14159265358979323846f;
#pragma unroll
        for (int d = 0; d < 4; ++d)
#pragma unroll
            for (int k = 0; k < 4; ++k) {
                float s, c;
                sincosf(xin[d] * (PI_F * (float)(1 << k)), &s, &c);
                enc[d * 8 + k]     = s;
                enc[d * 8 + 4 + k] = c;
            }
    }

    float h[64], h2[64], off[3];
    layer<32, 64, false>(Ww0, enc, A, h);
    layer<64, 64, true >(Ww1, h,   A, h2);
    layer<64, 3,  true >(Ww2, h2,  A, off);

    const float xn[3] = { (px + off[0] * MOVE_STEP + 1.5f) / 3.0f,
                          (py + off[1] * MOVE_STEP + 1.5f) / 3.0f,
                          (pz + off[2] * MOVE_STEP + 1.5f) / 3.0f };
    const bool sel = xn[0] > 0.f && xn[0] < 1.f && xn[1] > 0.f && xn[1] < 1.f &&
                     xn[2] > 0.f && xn[2] < 1.f;

    float feat[32];
#pragma unroll 2
    for (int l = 0; l < N_LVL; ++l) {
        const float scale = lp.scale[l];
        const int res = lp.res[l];
        float fr[3]; int c0[3];
#pragma unroll
        for (int d = 0; d < 3; ++d) {
            const float pp = xn[d] * scale + 0.5f;
            const float fl = floorf(pp);
            fr[d] = pp - fl;
            c0[d] = (int)fl;
        }
        const float* __restrict__ tbl = g_tab + (size_t)l * (size_t)(TBL * 2);
        float f0 = 0.f, f1 = 0.f;
        if (lp.dense[l]) {
#pragma unroll
            for (int c = 0; c < 8; ++c) {
                const int ci = (c >> 2) & 1, cj = (c >> 1) & 1, ck = c & 1;
                const unsigned idx = (unsigned)((c0[0] + ci) + res * ((c0[1] + cj) + res * (c0[2] + ck)));
                const float2 f = *reinterpret_cast<const float2*>(tbl + (size_t)idx * 2);
                const float w = (ci ? fr[0] : 1.f - fr[0]) * (cj ? fr[1] : 1.f - fr[1]) * (ck ? fr[2] : 1.f - fr[2]);
                f0 = fmaf(w, f.x, f0);
                f1 = fmaf(w, f.y, f1);
            }
        } else {
#pragma unroll
            for (int c = 0; c < 8; ++c) {
                const int ci = (c >> 2) & 1, cj = (c >> 1) & 1, ck = c & 1;
                const unsigned hx = (unsigned)(c0[0] + ci);
                const unsigned hy = (unsigned)(c0[1] + cj) * 2654435761u;
                const unsigned hz = (unsigned)(c0[2] + ck) * 805459861u;
                const unsigned idx = (hx ^ hy ^ hz) & (TBL - 1u);
                const float2 f = *reinterpret_cast<const float2*>(tbl + (size_t)idx * 2);
                const float w = (ci ? fr[0] : 1.f - fr[0]) * (cj ? fr[1] : 1.f - fr[1]) * (ck ? fr[2] : 1.f - fr[2]);
                f0 = fmaf(w, f.x, f0);
                f1 = fmaf(w, f.y, f1);
            }
        }
        feat[2 * l]     = f0;
        feat[2 * l + 1] = f1;
    }

    layer<32, 64, false>(Wb0, feat, A, h);
    float b[16];
    layer<64, 16, true >(Wb1, h, A, b);
    const float density = sel ? expf(b[0] - 1.0f) : 0.0f;

    float hin[31];
    {
        const float ddx = g_dir[3 * n + 0];
        const float ddy = g_dir[3 * n + 1];
        const float ddz = g_dir[3 * n + 2];
        const float nrm = sqrtf(ddx * ddx + ddy * ddy + ddz * ddz);
        const float x = ddx / nrm, y = ddy / nrm, z = ddz / nrm;
        const float xy = x * y, yz = y * z, xz = x * z;
        const float x2_ = x * x, y2 = y * y, z2 = z * z;
        hin[0]  = 0.28209479177387814f;
        hin[1]  = -0.48860251190291987f * y;
        hin[2]  = 0.48860251190291987f * z;
        hin[3]  = -0.48860251190291987f * x;
        hin[4]  = 1.0925484305920792f * xy;
        hin[5]  = -1.0925484305920792f * yz;
        hin[6]  = 0.94617469575756f * z2 - 0.31539156525252f;
        hin[7]  = -1.0925484305920792f * xz;
        hin[8]  = 0.5462742152960396f * (x2_ - y2);
        hin[9]  = 0.5900435899266435f * y * (y2 - 3.0f * x2_);
        hin[10] = 2.890611442640554f * xy * z;
        hin[11] = 0.4570457994644657f * y * (1.0f - 5.0f * z2);
        hin[12] = 0.3731763325901154f * z * (5.0f * z2 - 3.0f);
        hin[13] = 0.4570457994644657f * x * (1.0f - 5.0f * z2);
        hin[14] = 1.445305721320277f * z * (x2_ - y2);
        hin[15] = 0.5900435899266435f * x * (3.0f * y2 - x2_);
#pragma unroll
        for (int j = 0; j < 15; ++j) hin[16 + j] = b[1 + j];
    }

    layer<31, 64, false>(Wh0, hin, A, h);
    layer<64, 64, true >(Wh1, h,   A, h2);
    float rgb[3];
    layer<64, 3,  true >(Wh2, h2,  A, rgb);

    float4 o;
    o.x = 1.0f / (1.0f + expf(-rgb[0]));
    o.y = 1.0f / (1.0f + expf(-rgb[1]));
    o.z = 1.0f / (1.0f + expf(-rgb[2]));
    o.w = density;
    *reinterpret_cast<float4*>(g_out + (size_t)n * 4) = o;
}

extern "C" void kernel_launch(void* const* d_in, const int* in_sizes, int n_in,
                              void* d_out, int out_size, void* d_ws, size_t ws_size,
                              hipStream_t stream)
{
    const float* g_pos = (const float*)d_in[0];
    const float* g_t   = (const float*)d_in[1];
    const float* g_dir = (const float*)d_in[2];
    const float* g_tab = (const float*)d_in[3];
    const float* Ww0   = (const float*)d_in[4];
    const float* Ww1   = (const float*)d_in[5];
    const float* Ww2   = (const float*)d_in[6];
    const float* Wb0   = (const float*)d_in[7];
    const float* Wb1   = (const float*)d_in[8];
    const float* Wh0   = (const float*)d_in[9];
    const float* Wh1   = (const float*)d_in[10];
    const float* Wh2   = (const float*)d_in[11];
    const int N = in_sizes[0] / 3;

    LevelParams lp;
    int n_dense = 0;
    const double Bv = exp(log(4096.0 / 16.0) / 15.0);
    for (int l = 0; l < N_LVL; ++l) {
        const double s = 16.0 * pow(Bv, (double)l) - 1.0;
        lp.scale[l] = (float)s;
        const int r = (int)ceil(s) + 1;
        lp.res[l] = r;
        lp.dense[l] = ((long long)r * r * r <= (long long)TBL) ? 1 : 0;
        if (lp.dense[l]) n_dense = l + 1;
    }
    const int n_hashed = N_LVL - n_dense;

    const size_t stride = ((size_t)N + 259) & ~(size_t)3;
    const size_t ws_need = (size_t)C_TOT * 2048
                         + stride * 4 * 4              // xn4 plane (float4)
                         + stride * 4 * 16             // 16 packed feat planes
                         + (size_t)n_hashed * TBL * 4; // bf16x2 tables

    if (ws_size >= ws_need) {
        unsigned short* wfrag = (unsigned short*)d_ws;
        float* xn4 = (float*)((char*)d_ws + (size_t)C_TOT * 2048);
        unsigned* featp = (unsigned*)(xn4 + 4 * stride);
        unsigned* tab16 = featp + 16 * stride;

        AllLayers al;
        al.L[0] = { Ww0, 32, 64, 1, 4, C_W0 };
        al.L[1] = { Ww1, 64, 64, 2, 4, C_W1 };
        al.L[2] = { Ww2, 64,  3, 2, 1, C_W2 };
        al.L[3] = { Wb0, 32, 64, 1, 4, C_B0 };
        al.L[4] = { Wb1, 64, 16, 2, 1, C_B1 };
        al.L[5] = { Wh0, 31, 64, 1, 4, C_H0 };
        al.L[6] = { Wh1, 64, 64, 2, 4, C_H1 };
        al.L[7] = { Wh2, 64,  3, 2, 1, C_H2 };

        const int nchunk = (N + HTPB * HPTS - 1) / (HTPB * HPTS);

        dim3 mgrid((N + 127) / 128), mblock(256);
        dim3 hgrid(nchunk, n_hashed), hblock(HTPB);

        hipLaunchKernelGGL(k_prep, dim3(8), dim3(256), 0, stream, al, wfrag);
        hipLaunchKernelGGL(k_tab16, dim3(2048), dim3(256), 0, stream,
                           g_tab, tab16, n_dense, n_hashed);

        hipLaunchKernelGGL(k_warp_mfma, mgrid, mblock, 0, stream,
                           g_pos, g_t, g_tab, wfrag, xn4,
                           featp, stride, N, n_dense, lp);

        hipLaunchKernelGGL(k_hash_all16, hgrid, hblock, 0, stream,
                           tab16, xn4, featp, stride, N, n_dense, lp);

        hipLaunchKernelGGL(k_final_mfma, mgrid, mblock, 0, stream,
                           featp, stride, xn4, g_dir,
                           wfrag, (float*)d_out, N);
    } else {
        dim3 grid((N + TPB - 1) / TPB), block(TPB);
        hipLaunchKernelGGL(dngp_mono, grid, block, 0, stream,
                           g_pos, g_t, g_dir, g_tab,
                           Ww0, Ww1, Ww2, Wb0, Wb1, Wh0, Wh1, Wh2,
                           (float*)d_out, N, lp);
    }
}

// Round 13
// 248.940 us; speedup vs baseline: 1.6533x; 1.1122x over previous
//
#include <hip/hip_runtime.h>
#include <math.h>

#define TPB   128     // scalar fallback
#define HTPB  256
#define HPTS  4       // points per thread in hash kernel
#define CHUNK 32
#define LDW   68      // f32 LDS row stride: 272 B, 16B-aligned
constexpr int  N_LVL = 16;
constexpr unsigned TBL = 1u << 19;
constexpr float MOVE_STEP = 1.0f / 4096.0f;

typedef __attribute__((ext_vector_type(8))) short short8;
typedef __attribute__((ext_vector_type(4))) float f32x4;
// 8B-aligned float4 for dense x-pair loads (typedef may legally lower alignment)
typedef __attribute__((ext_vector_type(4), aligned(8))) float f32x4u;

struct LevelParams { float scale[N_LVL]; int res[N_LVL]; int dense[N_LVL]; };

// weight-fragment chunks (2048 B each = hi[64 lanes][short8] + lo[...])
enum { C_W0 = 0, C_W1 = 4, C_W2 = 12, C_B0 = 14, C_B1 = 18, C_H0 = 20, C_H1 = 24, C_H2 = 32, C_TOT = 34 };

struct LayerDesc { const float* W; int K; int N; int ksteps; int ntiles; int cbase; };
struct AllLayers { LayerDesc L[8]; };

__device__ __forceinline__ unsigned short f2bf(float x) {
    unsigned int u = __float_as_uint(x);
    u += 0x7FFFu + ((u >> 16) & 1u);            // RNE
    return (unsigned short)(u >> 16);
}
__device__ __forceinline__ float bf2f(unsigned short h) {
    return __uint_as_float(((unsigned int)h) << 16);
}
__device__ __forceinline__ unsigned pk(unsigned short a, unsigned short b) {
    return (unsigned)a | ((unsigned)b << 16);
}
// cndmask-tree select from a uint4 (no dynamic register indexing -> no scratch)
__device__ __forceinline__ unsigned sel4(uint4 w, unsigned i) {
    const unsigned lo = (i & 1u) ? w.y : w.x;
    const unsigned hi = (i & 1u) ? w.w : w.z;
    return (i & 2u) ? hi : lo;
}

// hw RNE pack: bf16(a) in [15:0], bf16(b) in [31:16]
__device__ __forceinline__ unsigned cvt_pk_bf16(float a, float b) {
    unsigned r;
    asm("v_cvt_pk_bf16_f32 %0, %1, %2" : "=v"(r) : "v"(a), "v"(b));
    return r;
}
// RNE hi/lo split of a float pair via cvt_pk. Same RNE as f2bf; residual exact.
__device__ __forceinline__ void split_pair(float a, float b, unsigned& hp, unsigned& lp) {
    hp = cvt_pk_bf16(a, b);
    const float ha = __uint_as_float(hp << 16);
    const float hb = __uint_as_float(hp & 0xffff0000u);
    lp = cvt_pk_bf16(a - ha, b - hb);
}

// ---------------------------------------------------------------------------
// prep: split weights into bf16 (hi,lo) MFMA B-fragments (RNE), per-lane order
// ---------------------------------------------------------------------------
__global__ __launch_bounds__(256) void k_prep(AllLayers al, unsigned short* __restrict__ wfrag)
{
    const LayerDesc d = al.L[blockIdx.x];
    const int total = d.ksteps * d.ntiles * 64;
    for (int slot = threadIdx.x; slot < total; slot += 256) {
        const int lane = slot & 63;
        const int c = slot >> 6;
        const int s = c / d.ntiles;
        const int t = c - s * d.ntiles;
        short8 hv, lv;
#pragma unroll
        for (int j = 0; j < 8; ++j) {
            const int k = s * 32 + ((lane >> 4) << 3) + j;
            const int n = t * 16 + (lane & 15);
            const float w = (k < d.K && n < d.N) ? d.W[k * d.N + n] : 0.f;
            const unsigned short hi = f2bf(w);
            const unsigned short lo = f2bf(w - bf2f(hi));
            hv[j] = (short)hi;
            lv[j] = (short)lo;
        }
        short8* b8 = reinterpret_cast<short8*>(wfrag + (size_t)(d.cbase + c) * 1024);
        b8[lane]      = hv;
        b8[64 + lane] = lv;
    }
}

// ---------------------------------------------------------------------------
// prep 2: convert hashed-level tables to packed bf16x2 (4 B/entry)
// ---------------------------------------------------------------------------
__global__ __launch_bounds__(256) void k_tab16(
    const float* __restrict__ g_tab, unsigned* __restrict__ tab16,
    int n_dense, int n_hashed)
{
    const size_t total_pairs = (size_t)n_hashed * (TBL / 2);
    const size_t gstride = (size_t)gridDim.x * 256;
    const float* __restrict__ src = g_tab + (size_t)n_dense * (TBL * 2);
    for (size_t i = (size_t)blockIdx.x * 256 + threadIdx.x; i < total_pairs; i += gstride) {
        const f32x4 v = reinterpret_cast<const f32x4*>(src)[i];
        uint2 o;
        o.x = pk(f2bf(v[0]), f2bf(v[1]));
        o.y = pk(f2bf(v[2]), f2bf(v[3]));
        reinterpret_cast<uint2*>(tab16)[i] = o;
    }
}

// ---------------------------------------------------------------------------
// wave dense layer: f32 LDS in, per-k-step RNE hi/lo split (cvt_pk), 3-term
// MFMA (hh + lh + hl), f32 LDS out. In-place on one buffer (proven R7).
// ---------------------------------------------------------------------------
template<int KSTEPS, int NTILES, bool RELU>
__device__ __forceinline__ void wave_layer(float* X,
                                           const unsigned short* __restrict__ wfrag, int cbase,
                                           int wrow, int lane)
{
    f32x4 acc[2][NTILES];
#pragma unroll
    for (int ms = 0; ms < 2; ++ms)
#pragma unroll
        for (int t = 0; t < NTILES; ++t) acc[ms][t] = f32x4{0.f, 0.f, 0.f, 0.f};
    const int r15 = lane & 15, q = lane >> 4;
    const short8* wf8 = reinterpret_cast<const short8*>(wfrag) + (size_t)cbase * 128;
#pragma unroll
    for (int s = 0; s < KSTEPS; ++s) {
        short8 ah[2], al[2];
#pragma unroll
        for (int ms = 0; ms < 2; ++ms) {
            const float* xp = X + (size_t)(wrow + ms * 16 + r15) * LDW + s * 32 + q * 8;
            const f32x4 x0 = reinterpret_cast<const f32x4*>(xp)[0];
            const f32x4 x1 = reinterpret_cast<const f32x4*>(xp)[1];
            union { unsigned u[4]; short8 s8; } uh, ul;
            split_pair(x0[0], x0[1], uh.u[0], ul.u[0]);
            split_pair(x0[2], x0[3], uh.u[1], ul.u[1]);
            split_pair(x1[0], x1[1], uh.u[2], ul.u[2]);
            split_pair(x1[2], x1[3], uh.u[3], ul.u[3]);
            ah[ms] = uh.s8;
            al[ms] = ul.s8;
        }
#pragma unroll
        for (int t = 0; t < NTILES; ++t) {
            const short8* cp = wf8 + (size_t)(s * NTILES + t) * 128;
            const short8 bh = cp[lane];
            const short8 bl = cp[64 + lane];
#pragma unroll
            for (int ms = 0; ms < 2; ++ms) {
                acc[ms][t] = __builtin_amdgcn_mfma_f32_16x16x32_bf16(ah[ms], bh, acc[ms][t], 0, 0, 0);
                acc[ms][t] = __builtin_amdgcn_mfma_f32_16x16x32_bf16(al[ms], bh, acc[ms][t], 0, 0, 0);
                acc[ms][t] = __builtin_amdgcn_mfma_f32_16x16x32_bf16(ah[ms], bl, acc[ms][t], 0, 0, 0);
            }
        }
    }
#pragma unroll
    for (int ms = 0; ms < 2; ++ms)
#pragma unroll
        for (int t = 0; t < NTILES; ++t)
#pragma unroll
            for (int r = 0; r < 4; ++r) {
                float v = acc[ms][t][r];
                if (RELU) v = fmaxf(v, 0.f);
                X[(size_t)(wrow + ms * 16 + q * 4 + r) * LDW + t * 16 + r15] = v;
            }
}

// ---------------------------------------------------------------------------
// Kernel 1: freq encode + warp MLP (MFMA) -> xn4 plane + DENSE hash levels.
// Epilogue is PER-WAVE (no final barrier): each wave's 64 lanes handle its own
// 32 rows (2 lanes/point: sub0 = levels [0,dmid) + xn store, sub1 = [dmid,nd)).
// Dense gathers use f32x4 x-pair loads (corners x,x+1 adjacent): 4 loads/level.
// ---------------------------------------------------------------------------
__global__ __launch_bounds__(256, 4) void k_warp_mfma(
    const float* __restrict__ g_pos, const float* __restrict__ g_t,
    const float* __restrict__ g_tab,
    const unsigned short* __restrict__ wfrag,
    float* __restrict__ xn4,
    unsigned* __restrict__ featp, size_t stride, int N, int n_dense, LevelParams lp)
{
    __shared__ float buf[128 * LDW];        // 34.8 KB
    const int tid = threadIdx.x;
    const int base = blockIdx.x * 128;
    const int p = tid & 127;
    const int pn = min(base + p, N - 1);
    const float PI_F = 3.14159265358979323846f;

    {   // enc staging: thread-pairs split the 4 input dims
        const int dpair = tid >> 7;
        float v0, v1;
        if (dpair == 0) { v0 = g_pos[3 * pn + 0]; v1 = g_pos[3 * pn + 1]; }
        else            { v0 = g_pos[3 * pn + 2]; v1 = g_t[pn]; }
#pragma unroll
        for (int e = 0; e < 2; ++e) {
            const float x = e ? v1 : v0;
            const int d = dpair * 2 + e;
            f32x4 sv, cv;
#pragma unroll
            for (int k = 0; k < 4; ++k) {
                const float a = x * (PI_F * (float)(1 << k));
                sv[k] = __sinf(a);
                cv[k] = __cosf(a);
            }
            *reinterpret_cast<f32x4*>(&buf[(size_t)p * LDW + d * 8])     = sv;
            *reinterpret_cast<f32x4*>(&buf[(size_t)p * LDW + d * 8 + 4]) = cv;
        }
    }
    __syncthreads();
    const int lane = tid & 63, wrow = (tid >> 6) * 32;
    wave_layer<1, 4, true >(buf, wfrag, C_W0, wrow, lane);
    wave_layer<2, 4, true >(buf, wfrag, C_W1, wrow, lane);
    wave_layer<2, 1, false>(buf, wfrag, C_W2, wrow, lane);
    // NO final barrier: epilogue reads only rows [wrow, wrow+32) written by
    // this wave; same-wave DS ops are ordered.

    const int prow = wrow + (lane & 31);
    const int sub  = lane >> 5;
    const int n = base + prow;
    const int pn2 = min(n, N - 1);
    const float ox = buf[(size_t)prow * LDW + 0];
    const float oy = buf[(size_t)prow * LDW + 1];
    const float oz = buf[(size_t)prow * LDW + 2];
    const float xnv[3] = { (g_pos[3 * pn2 + 0] + ox * MOVE_STEP + 1.5f) / 3.0f,
                           (g_pos[3 * pn2 + 1] + oy * MOVE_STEP + 1.5f) / 3.0f,
                           (g_pos[3 * pn2 + 2] + oz * MOVE_STEP + 1.5f) / 3.0f };
    if (sub == 0 && n < N) {
        reinterpret_cast<f32x4*>(xn4)[n] = f32x4{ xnv[0], xnv[1], xnv[2], 0.f };
    }

    const int dmid = min(3, n_dense);
    const int l0 = sub ? dmid : 0;
    const int l1 = sub ? n_dense : dmid;
    for (int l = l0; l < l1; ++l) {
        const float scale = lp.scale[l];
        const int res = lp.res[l];
        float fr[3]; int c0[3];
#pragma unroll
        for (int d = 0; d < 3; ++d) {
            const float pp = xnv[d] * scale + 0.5f;
            const float fl = floorf(pp);
            fr[d] = pp - fl;
            c0[d] = (int)fl;
        }
        const float* __restrict__ tbl = g_tab + (size_t)l * (size_t)(TBL * 2);
        f32x4u v[4];
#pragma unroll
        for (int pc = 0; pc < 4; ++pc) {
            const int cj = pc >> 1, ck = pc & 1;
            const int idx = c0[0] + res * ((c0[1] + cj) + res * (c0[2] + ck));
            v[pc] = *reinterpret_cast<const f32x4u*>(tbl + (size_t)idx * 2);
        }
        float f0 = 0.f, f1 = 0.f;
        const float wx0 = 1.f - fr[0], wx1 = fr[0];
#pragma unroll
        for (int pc = 0; pc < 4; ++pc) {
            const int cj = pc >> 1, ck = pc & 1;
            const float wyz = (cj ? fr[1] : 1.f - fr[1]) * (ck ? fr[2] : 1.f - fr[2]);
            f0 = fmaf(wx0 * wyz, v[pc][0], f0);
            f1 = fmaf(wx0 * wyz, v[pc][1], f1);
            f0 = fmaf(wx1 * wyz, v[pc][2], f0);
            f1 = fmaf(wx1 * wyz, v[pc][3], f1);
        }
        if (n < N) {
            __builtin_nontemporal_store(pk(f2bf(f0), f2bf(f1)), &featp[(size_t)l * stride + n]);
        }
    }
}

// ---------------------------------------------------------------------------
// Kernel 2 (bf16 tables): all hashed levels, level = blockIdx.y.
// uint4 pair trick: iB = iA ^ (x^(x+1)); mask <= 3 for 75% of x, so one 16B
// gather at (iA & ~3) covers both x-corners; x%4==3 issues 4 predicated u32.
// Avg 5 gathers/pt-level (was 6). Batches of 2 points cap VGPR.
// ---------------------------------------------------------------------------
__global__ __launch_bounds__(HTPB) void k_hash_all16(
    const unsigned* __restrict__ tab16,
    const float* __restrict__ xn4,
    unsigned* __restrict__ featp, size_t stride, int N, int n_dense, LevelParams lp)
{
    const int l = n_dense + blockIdx.y;
    const float scale = lp.scale[l];
    const unsigned* __restrict__ tbl = tab16 + (size_t)blockIdx.y * TBL;
    unsigned* __restrict__ op = featp + (size_t)l * stride;

    const int base = blockIdx.x * (HTPB * HPTS) + threadIdx.x;

#pragma unroll
    for (int b = 0; b < HPTS; b += 2) {
        int nn[2]; bool av[2];
        f32x4 xs[2];
#pragma unroll
        for (int j = 0; j < 2; ++j) {
            nn[j] = base + (b + j) * HTPB;
            av[j] = nn[j] < N;
            xs[j] = reinterpret_cast<const f32x4*>(xn4)[av[j] ? nn[j] : 0];
        }

        float frx[2];
        float wyz[2][4];
        uint4 w4[2][4];
        unsigned vodd[2][4] = {};
        unsigned a3p[2], mm[2];
        bool far_[2];
#pragma unroll
        for (int j = 0; j < 2; ++j) {
            int c0[3]; float fr[3];
#pragma unroll
            for (int d = 0; d < 3; ++d) {
                const float pp = xs[j][d] * scale + 0.5f;
                const float fl = floorf(pp);
                fr[d] = pp - fl;
                c0[d] = (int)fl;
            }
            frx[j] = fr[0];
            const unsigned ux  = (unsigned)c0[0];
            const unsigned ry0 = (unsigned)c0[1] * 2654435761u;
            const unsigned ry1 = (unsigned)(c0[1] + 1) * 2654435761u;
            const unsigned rz0 = (unsigned)c0[2] * 805459861u;
            const unsigned rz1 = (unsigned)(c0[2] + 1) * 805459861u;
            mm[j]  = ux ^ (ux + 1u);
            far_[j] = mm[j] > 3u;
            const float wy0 = 1.f - fr[1], wy1 = fr[1];
            const float wz0 = 1.f - fr[2], wz1 = fr[2];
            wyz[j][0] = wy0 * wz0; wyz[j][1] = wy0 * wz1;
            wyz[j][2] = wy1 * wz0; wyz[j][3] = wy1 * wz1;
            const unsigned rr[4] = { ry0 ^ rz0, ry0 ^ rz1, ry1 ^ rz0, ry1 ^ rz1 };
            unsigned a3 = 0;
#pragma unroll
            for (int pc = 0; pc < 4; ++pc) {
                const unsigned iA = (ux ^ rr[pc]) & (TBL - 1u);
                a3 |= (iA & 3u) << (2 * pc);
                w4[j][pc] = *reinterpret_cast<const uint4*>(tbl + (iA & ~3u));
            }
            a3p[j] = a3;
            if (far_[j]) {
#pragma unroll
                for (int pc = 0; pc < 4; ++pc) {
                    const unsigned iB = ((ux + 1u) ^ rr[pc]) & (TBL - 1u);
                    vodd[j][pc] = tbl[iB];
                }
            }
        }

#pragma unroll
        for (int j = 0; j < 2; ++j) {
            float f0 = 0.f, f1 = 0.f;
            const float wx0 = 1.f - frx[j], wx1 = frx[j];
#pragma unroll
            for (int pc = 0; pc < 4; ++pc) {
                const unsigned a3 = (a3p[j] >> (2 * pc)) & 3u;
                const unsigned vA = sel4(w4[j][pc], a3);
                const unsigned vB = far_[j] ? vodd[j][pc] : sel4(w4[j][pc], a3 ^ mm[j]);
                const float wA = wx0 * wyz[j][pc];
                const float wB = wx1 * wyz[j][pc];
                f0 = fmaf(wA, bf2f((unsigned short)(vA & 0xffffu)), f0);
                f1 = fmaf(wA, bf2f((unsigned short)(vA >> 16)), f1);
                f0 = fmaf(wB, bf2f((unsigned short)(vB & 0xffffu)), f0);
                f1 = fmaf(wB, bf2f((unsigned short)(vB >> 16)), f1);
            }
            if (av[j]) __builtin_nontemporal_store(pk(f2bf(f0), f2bf(f1)), &op[nn[j]]);
        }
    }
}

// ---------------------------------------------------------------------------
// Kernel 3: base MLP + SH + head MLP (MFMA) -> output
// ---------------------------------------------------------------------------
__global__ __launch_bounds__(256, 4) void k_final_mfma(
    const unsigned* __restrict__ featp, size_t stride,
    const float* __restrict__ xn4,
    const float* __restrict__ g_dir,
    const unsigned short* __restrict__ wfrag,
    float* __restrict__ g_out, int N)
{
    __shared__ float buf[128 * LDW];        // 34.8 KB
    const int tid = threadIdx.x;
    const int base = blockIdx.x * 128;
    const int p = tid & 127;
    const int pn = min(base + p, N - 1);
    const int g = tid >> 7;

    // stage 16 packed feat planes -> buf[p][0..31] (unpack bf16 -> f32)
#pragma unroll
    for (int j = 0; j < 8; ++j) {
        const int l = g * 8 + j;
        const unsigned v = __builtin_nontemporal_load(&featp[(size_t)l * stride + pn]);
        buf[(size_t)p * LDW + 2 * l]     = bf2f((unsigned short)(v & 0xffffu));
        buf[(size_t)p * LDW + 2 * l + 1] = bf2f((unsigned short)(v >> 16));
    }
    __syncthreads();

    const int lane = tid & 63, wrow = (tid >> 6) * 32;
    wave_layer<1, 4, true >(buf, wfrag, C_B0, wrow, lane);
    wave_layer<2, 1, false>(buf, wfrag, C_B1, wrow, lane);
    __syncthreads();

    float density = 0.f;
    if (tid < 128) {
        float bb[16];
        const f32x4* bv = reinterpret_cast<const f32x4*>(&buf[(size_t)tid * LDW]);
#pragma unroll
        for (int g4 = 0; g4 < 4; ++g4) {
            const f32x4 v = bv[g4];
#pragma unroll
            for (int j = 0; j < 4; ++j) bb[4 * g4 + j] = v[j];
        }
        const f32x4 xv = reinterpret_cast<const f32x4*>(xn4)[pn];
        const bool sel = xv[0] > 0.f && xv[0] < 1.f && xv[1] > 0.f && xv[1] < 1.f &&
                         xv[2] > 0.f && xv[2] < 1.f;
        density = sel ? expf(bb[0] - 1.0f) : 0.0f;

        const float ddx = g_dir[3 * pn + 0];
        const float ddy = g_dir[3 * pn + 1];
        const float ddz = g_dir[3 * pn + 2];
        const float nrm = sqrtf(ddx * ddx + ddy * ddy + ddz * ddz);
        const float x = ddx / nrm, y = ddy / nrm, z = ddz / nrm;
        const float xy = x * y, yz = y * z, xz = x * z;
        const float x2 = x * x, y2 = y * y, z2 = z * z;
        f32x4 o0, o1, o2, o3, o4, o5, o6, o7;
        o0[0] = 0.28209479177387814f;
        o0[1] = -0.48860251190291987f * y;
        o0[2] = 0.48860251190291987f * z;
        o0[3] = -0.48860251190291987f * x;
        o1[0] = 1.0925484305920792f * xy;
        o1[1] = -1.0925484305920792f * yz;
        o1[2] = 0.94617469575756f * z2 - 0.31539156525252f;
        o1[3] = -1.0925484305920792f * xz;
        o2[0] = 0.5462742152960396f * (x2 - y2);
        o2[1] = 0.5900435899266435f * y * (y2 - 3.0f * x2);
        o2[2] = 2.890611442640554f * xy * z;
        o2[3] = 0.4570457994644657f * y * (1.0f - 5.0f * z2);
        o3[0] = 0.3731763325901154f * z * (5.0f * z2 - 3.0f);
        o3[1] = 0.4570457994644657f * x * (1.0f - 5.0f * z2);
        o3[2] = 1.445305721320277f * z * (x2 - y2);
        o3[3] = 0.5900435899266435f * x * (3.0f * y2 - x2);
        o4[0] = bb[1];  o4[1] = bb[2];  o4[2] = bb[3];  o4[3] = bb[4];
        o5[0] = bb[5];  o5[1] = bb[6];  o5[2] = bb[7];  o5[3] = bb[8];
        o6[0] = bb[9];  o6[1] = bb[10]; o6[2] = bb[11]; o6[3] = bb[12];
        o7[0] = bb[13]; o7[1] = bb[14]; o7[2] = bb[15]; o7[3] = 0.f;
        f32x4* wb = reinterpret_cast<f32x4*>(&buf[(size_t)tid * LDW]);
        wb[0] = o0; wb[1] = o1; wb[2] = o2; wb[3] = o3;
        wb[4] = o4; wb[5] = o5; wb[6] = o6; wb[7] = o7;
    }
    __syncthreads();

    wave_layer<1, 4, true >(buf, wfrag, C_H0, wrow, lane);
    wave_layer<2, 4, true >(buf, wfrag, C_H1, wrow, lane);
    wave_layer<2, 1, false>(buf, wfrag, C_H2, wrow, lane);
    __syncthreads();

    if (tid < 128 && base + tid < N) {
        const int n = base + tid;
        float4 o;
        o.x = 1.0f / (1.0f + expf(-buf[(size_t)tid * LDW + 0]));
        o.y = 1.0f / (1.0f + expf(-buf[(size_t)tid * LDW + 1]));
        o.z = 1.0f / (1.0f + expf(-buf[(size_t)tid * LDW + 2]));
        o.w = density;
        *reinterpret_cast<float4*>(g_out + (size_t)n * 4) = o;
    }
}

// ---------------------------------------------------------------------------
// Scalar fallback (round-2 monolith) used only if ws too small
// ---------------------------------------------------------------------------
template<int IN, int OUT, bool RELU>
__device__ __forceinline__ void layer(const float* __restrict__ W,
                                      const float* __restrict__ hin,
                                      float* __restrict__ A,
                                      float* __restrict__ out)
{
#pragma unroll
    for (int j = 0; j < OUT; ++j) out[j] = 0.f;
#pragma unroll
    for (int c = 0; c < IN; c += CHUNK) {
#pragma unroll
        for (int i = 0; i < CHUNK; ++i) {
            if (c + i < IN) A[i * TPB] = RELU ? fmaxf(hin[c + i], 0.f) : hin[c + i];
        }
        const int cnt = (IN - c < CHUNK) ? (IN - c) : CHUNK;
#pragma unroll 4
        for (int i = 0; i < cnt; ++i) {
            const float a = A[i * TPB];
            const float* __restrict__ Wr = W + (size_t)(c + i) * OUT;
#pragma unroll
            for (int j = 0; j < OUT; ++j)
                out[j] = fmaf(a, Wr[j], out[j]);
        }
    }
}

__global__ __launch_bounds__(TPB, 4) void dngp_mono(
    const float* __restrict__ g_pos, const float* __restrict__ g_t,
    const float* __restrict__ g_dir, const float* __restrict__ g_tab,
    const float* __restrict__ Ww0, const float* __restrict__ Ww1, const float* __restrict__ Ww2,
    const float* __restrict__ Wb0, const float* __restrict__ Wb1,
    const float* __restrict__ Wh0, const float* __restrict__ Wh1, const float* __restrict__ Wh2,
    float* __restrict__ g_out, int N, LevelParams lp)
{
    __shared__ float s_act[CHUNK * TPB];
    const int tid = threadIdx.x;
    const int n = blockIdx.x * TPB + tid;
    if (n >= N) return;
    float* __restrict__ A = s_act + tid;

    const float px = g_pos[3 * n + 0];
    const float py = g_pos[3 * n + 1];
    const float pz = g_pos[3 * n + 2];
    const float tt = g_t[n];

    float enc[32];
    {
        const float xin[4] = { px, py, pz, tt };
        const float PI_F = 3.14159265358979323846f;
#pragma unroll
        for (int d = 0; d < 4; ++d)
#pragma unroll
            for (int k = 0; k < 4; ++k) {
                float s, c;
                sincosf(xin[d] * (PI_F * (float)(1 << k)), &s, &c);
                enc[d * 8 + k]     = s;
                enc[d * 8 + 4 + k] = c;
            }
    }

    float h[64], h2[64], off[3];
    layer<32, 64, false>(Ww0, enc, A, h);
    layer<64, 64, true >(Ww1, h,   A, h2);
    layer<64, 3,  true >(Ww2, h2,  A, off);

    const float xn[3] = { (px + off[0] * MOVE_STEP + 1.5f) / 3.0f,
                          (py + off[1] * MOVE_STEP + 1.5f) / 3.0f,
                          (pz + off[2] * MOVE_STEP + 1.5f) / 3.0f };
    const bool sel = xn[0] > 0.f && xn[0] < 1.f && xn[1] > 0.f && xn[1] < 1.f &&
                     xn[2] > 0.f && xn[2] < 1.f;

    float feat[32];
#pragma unroll 2
    for (int l = 0; l < N_LVL; ++l) {
        const float scale = lp.scale[l];
        const int res = lp.res[l];
        float fr[3]; int c0[3];
#pragma unroll
        for (int d = 0; d < 3; ++d) {
            const float pp = xn[d] * scale + 0.5f;
            const float fl = floorf(pp);
            fr[d] = pp - fl;
            c0[d] = (int)fl;
        }
        const float* __restrict__ tbl = g_tab + (size_t)l * (size_t)(TBL * 2);
        float f0 = 0.f, f1 = 0.f;
        if (lp.dense[l]) {
#pragma unroll
            for (int c = 0; c < 8; ++c) {
                const int ci = (c >> 2) & 1, cj = (c >> 1) & 1, ck = c & 1;
                const unsigned idx = (unsigned)((c0[0] + ci) + res * ((c0[1] + cj) + res * (c0[2] + ck)));
                const float2 f = *reinterpret_cast<const float2*>(tbl + (size_t)idx * 2);
                const float w = (ci ? fr[0] : 1.f - fr[0]) * (cj ? fr[1] : 1.f - fr[1]) * (ck ? fr[2] : 1.f - fr[2]);
                f0 = fmaf(w, f.x, f0);
                f1 = fmaf(w, f.y, f1);
            }
        } else {
#pragma unroll
            for (int c = 0; c < 8; ++c) {
                const int ci = (c >> 2) & 1, cj = (c >> 1) & 1, ck = c & 1;
                const unsigned hx = (unsigned)(c0[0] + ci);
                const unsigned hy = (unsigned)(c0[1] + cj) * 2654435761u;
                const unsigned hz = (unsigned)(c0[2] + ck) * 805459861u;
                const unsigned idx = (hx ^ hy ^ hz) & (TBL - 1u);
                const float2 f = *reinterpret_cast<const float2*>(tbl + (size_t)idx * 2);
                const float w = (ci ? fr[0] : 1.f - fr[0]) * (cj ? fr[1] : 1.f - fr[1]) * (ck ? fr[2] : 1.f - fr[2]);
                f0 = fmaf(w, f.x, f0);
                f1 = fmaf(w, f.y, f1);
            }
        }
        feat[2 * l]     = f0;
        feat[2 * l + 1] = f1;
    }

    layer<32, 64, false>(Wb0, feat, A, h);
    float b[16];
    layer<64, 16, true >(Wb1, h, A, b);
    const float density = sel ? expf(b[0] - 1.0f) : 0.0f;

    float hin[31];
    {
        const float ddx = g_dir[3 * n + 0];
        const float ddy = g_dir[3 * n + 1];
        const float ddz = g_dir[3 * n + 2];
        const float nrm = sqrtf(ddx * ddx + ddy * ddy + ddz * ddz);
        const float x = ddx / nrm, y = ddy / nrm, z = ddz / nrm;
        const float xy = x * y, yz = y * z, xz = x * z;
        const float x2_ = x * x, y2 = y * y, z2 = z * z;
        hin[0]  = 0.28209479177387814f;
        hin[1]  = -0.48860251190291987f * y;
        hin[2]  = 0.48860251190291987f * z;
        hin[3]  = -0.48860251190291987f * x;
        hin[4]  = 1.0925484305920792f * xy;
        hin[5]  = -1.0925484305920792f * yz;
        hin[6]  = 0.94617469575756f * z2 - 0.31539156525252f;
        hin[7]  = -1.0925484305920792f * xz;
        hin[8]  = 0.5462742152960396f * (x2_ - y2);
        hin[9]  = 0.5900435899266435f * y * (y2 - 3.0f * x2_);
        hin[10] = 2.890611442640554f * xy * z;
        hin[11] = 0.4570457994644657f * y * (1.0f - 5.0f * z2);
        hin[12] = 0.3731763325901154f * z * (5.0f * z2 - 3.0f);
        hin[13] = 0.4570457994644657f * x * (1.0f - 5.0f * z2);
        hin[14] = 1.445305721320277f * z * (x2_ - y2);
        hin[15] = 0.5900435899266435f * x * (3.0f * y2 - x2_);
#pragma unroll
        for (int j = 0; j < 15; ++j) hin[16 + j] = b[1 + j];
    }

    layer<31, 64, false>(Wh0, hin, A, h);
    layer<64, 64, true >(Wh1, h,   A, h2);
    float rgb[3];
    layer<64, 3,  true >(Wh2, h2,  A, rgb);

    float4 o;
    o.x = 1.0f / (1.0f + expf(-rgb[0]));
    o.y = 1.0f / (1.0f + expf(-rgb[1]));
    o.z = 1.0f / (1.0f + expf(-rgb[2]));
    o.w = density;
    *reinterpret_cast<float4*>(g_out + (size_t)n * 4) = o;
}

extern "C" void kernel_launch(void* const* d_in, const int* in_sizes, int n_in,
                              void* d_out, int out_size, void* d_ws, size_t ws_size,
                              hipStream_t stream)
{
    const float* g_pos = (const float*)d_in[0];
    const float* g_t   = (const float*)d_in[1];
    const float* g_dir = (const float*)d_in[2];
    const float* g_tab = (const float*)d_in[3];
    const float* Ww0   = (const float*)d_in[4];
    const float* Ww1   = (const float*)d_in[5];
    const float* Ww2   = (const float*)d_in[6];
    const float* Wb0   = (const float*)d_in[7];
    const float* Wb1   = (const float*)d_in[8];
    const float* Wh0   = (const float*)d_in[9];
    const float* Wh1   = (const float*)d_in[10];
    const float* Wh2   = (const float*)d_in[11];
    const int N = in_sizes[0] / 3;

    LevelParams lp;
    int n_dense = 0;
    const double Bv = exp(log(4096.0 / 16.0) / 15.0);
    for (int l = 0; l < N_LVL; ++l) {
        const double s = 16.0 * pow(Bv, (double)l) - 1.0;
        lp.scale[l] = (float)s;
        const int r = (int)ceil(s) + 1;
        lp.res[l] = r;
        lp.dense[l] = ((long long)r * r * r <= (long long)TBL) ? 1 : 0;
        if (lp.dense[l]) n_dense = l + 1;
    }
    const int n_hashed = N_LVL - n_dense;

    const size_t stride = ((size_t)N + 259) & ~(size_t)3;
    const size_t ws_need = (size_t)C_TOT * 2048
                         + stride * 4 * 4              // xn4 plane (float4)
                         + stride * 4 * 16             // 16 packed feat planes
                         + (size_t)n_hashed * TBL * 4; // bf16x2 tables

    if (ws_size >= ws_need) {
        unsigned short* wfrag = (unsigned short*)d_ws;
        float* xn4 = (float*)((char*)d_ws + (size_t)C_TOT * 2048);
        unsigned* featp = (unsigned*)(xn4 + 4 * stride);
        unsigned* tab16 = featp + 16 * stride;

        AllLayers al;
        al.L[0] = { Ww0, 32, 64, 1, 4, C_W0 };
        al.L[1] = { Ww1, 64, 64, 2, 4, C_W1 };
        al.L[2] = { Ww2, 64,  3, 2, 1, C_W2 };
        al.L[3] = { Wb0, 32, 64, 1, 4, C_B0 };
        al.L[4] = { Wb1, 64, 16, 2, 1, C_B1 };
        al.L[5] = { Wh0, 31, 64, 1, 4, C_H0 };
        al.L[6] = { Wh1, 64, 64, 2, 4, C_H1 };
        al.L[7] = { Wh2, 64,  3, 2, 1, C_H2 };

        const int nchunk = (N + HTPB * HPTS - 1) / (HTPB * HPTS);

        dim3 mgrid((N + 127) / 128), mblock(256);
        dim3 hgrid(nchunk, n_hashed), hblock(HTPB);

        hipLaunchKernelGGL(k_prep, dim3(8), dim3(256), 0, stream, al, wfrag);
        hipLaunchKernelGGL(k_tab16, dim3(2048), dim3(256), 0, stream,
                           g_tab, tab16, n_dense, n_hashed);

        hipLaunchKernelGGL(k_warp_mfma, mgrid, mblock, 0, stream,
                           g_pos, g_t, g_tab, wfrag, xn4,
                           featp, stride, N, n_dense, lp);

        hipLaunchKernelGGL(k_hash_all16, hgrid, hblock, 0, stream,
                           tab16, xn4, featp, stride, N, n_dense, lp);

        hipLaunchKernelGGL(k_final_mfma, mgrid, mblock, 0, stream,
                           featp, stride, xn4, g_dir,
                           wfrag, (float*)d_out, N);
    } else {
        dim3 grid((N + TPB - 1) / TPB), block(TPB);
        hipLaunchKernelGGL(dngp_mono, grid, block, 0, stream,
                           g_pos, g_t, g_dir, g_tab,
                           Ww0, Ww1, Ww2, Wb0, Wb1, Wh0, Wh1, Wh2,
                           (float*)d_out, N, lp);
    }
}

// Round 14
// 238.164 us; speedup vs baseline: 1.7281x; 1.0452x over previous
//
#include <hip/hip_runtime.h>
#include <math.h>

#define TPB   128     // scalar fallback
#define HTPB  256
#define HPTS  4       // points per thread in hash kernel
#define CHUNK 32
#define LDW   68      // f32 LDS row stride: 272 B, 16B-aligned
constexpr int  N_LVL = 16;
constexpr unsigned TBL = 1u << 19;
constexpr float MOVE_STEP = 1.0f / 4096.0f;

typedef __attribute__((ext_vector_type(8))) short short8;
typedef __attribute__((ext_vector_type(4))) float f32x4;
// 8B-aligned float4 for dense x-pair loads
typedef __attribute__((ext_vector_type(4), aligned(8))) float f32x4u;

struct LevelParams { float scale[N_LVL]; int res[N_LVL]; int dense[N_LVL]; };

// weight-fragment chunks (2048 B each = hi[64 lanes][short8] + lo[...])
enum { C_W0 = 0, C_W1 = 4, C_W2 = 12, C_B0 = 14, C_B1 = 18, C_H0 = 20, C_H1 = 24, C_H2 = 32, C_TOT = 34 };

struct LayerDesc { const float* W; int K; int N; int ksteps; int ntiles; int cbase; };
struct AllLayers { LayerDesc L[8]; };

__device__ __forceinline__ unsigned short f2bf(float x) {
    unsigned int u = __float_as_uint(x);
    u += 0x7FFFu + ((u >> 16) & 1u);            // RNE
    return (unsigned short)(u >> 16);
}
__device__ __forceinline__ float bf2f(unsigned short h) {
    return __uint_as_float(((unsigned int)h) << 16);
}
__device__ __forceinline__ unsigned pk(unsigned short a, unsigned short b) {
    return (unsigned)a | ((unsigned)b << 16);
}
// cndmask-tree select from a uint4 (no dynamic register indexing -> no scratch)
__device__ __forceinline__ unsigned sel4(uint4 w, unsigned i) {
    const unsigned lo = (i & 1u) ? w.y : w.x;
    const unsigned hi = (i & 1u) ? w.w : w.z;
    return (i & 2u) ? hi : lo;
}

// hw RNE pack: bf16(a) in [15:0], bf16(b) in [31:16]
__device__ __forceinline__ unsigned cvt_pk_bf16(float a, float b) {
    unsigned r;
    asm("v_cvt_pk_bf16_f32 %0, %1, %2" : "=v"(r) : "v"(a), "v"(b));
    return r;
}
// RNE hi/lo split of a float pair via cvt_pk. Same RNE as f2bf; residual exact.
__device__ __forceinline__ void split_pair(float a, float b, unsigned& hp, unsigned& lp) {
    hp = cvt_pk_bf16(a, b);
    const float ha = __uint_as_float(hp << 16);
    const float hb = __uint_as_float(hp & 0xffff0000u);
    lp = cvt_pk_bf16(a - ha, b - hb);
}

// ---------------------------------------------------------------------------
// prep: split weights into bf16 (hi,lo) MFMA B-fragments (RNE), per-lane order
// ---------------------------------------------------------------------------
__global__ __launch_bounds__(256) void k_prep(AllLayers al, unsigned short* __restrict__ wfrag)
{
    const LayerDesc d = al.L[blockIdx.x];
    const int total = d.ksteps * d.ntiles * 64;
    for (int slot = threadIdx.x; slot < total; slot += 256) {
        const int lane = slot & 63;
        const int c = slot >> 6;
        const int s = c / d.ntiles;
        const int t = c - s * d.ntiles;
        short8 hv, lv;
#pragma unroll
        for (int j = 0; j < 8; ++j) {
            const int k = s * 32 + ((lane >> 4) << 3) + j;
            const int n = t * 16 + (lane & 15);
            const float w = (k < d.K && n < d.N) ? d.W[k * d.N + n] : 0.f;
            const unsigned short hi = f2bf(w);
            const unsigned short lo = f2bf(w - bf2f(hi));
            hv[j] = (short)hi;
            lv[j] = (short)lo;
        }
        short8* b8 = reinterpret_cast<short8*>(wfrag + (size_t)(d.cbase + c) * 1024);
        b8[lane]      = hv;
        b8[64 + lane] = lv;
    }
}

// ---------------------------------------------------------------------------
// prep 2: convert hashed-level tables to packed bf16x2 (4 B/entry)
// ---------------------------------------------------------------------------
__global__ __launch_bounds__(256) void k_tab16(
    const float* __restrict__ g_tab, unsigned* __restrict__ tab16,
    int n_dense, int n_hashed)
{
    const size_t total_pairs = (size_t)n_hashed * (TBL / 2);
    const size_t gstride = (size_t)gridDim.x * 256;
    const float* __restrict__ src = g_tab + (size_t)n_dense * (TBL * 2);
    for (size_t i = (size_t)blockIdx.x * 256 + threadIdx.x; i < total_pairs; i += gstride) {
        const f32x4 v = reinterpret_cast<const f32x4*>(src)[i];
        uint2 o;
        o.x = pk(f2bf(v[0]), f2bf(v[1]));
        o.y = pk(f2bf(v[2]), f2bf(v[3]));
        reinterpret_cast<uint2*>(tab16)[i] = o;
    }
}

// ---------------------------------------------------------------------------
// wave dense layer: f32 LDS in, per-k-step RNE split (cvt_pk), TERMS-term MFMA
// (TERMS=3: hh+lh+hl full fp32-emulation; TERMS=1: hh only — used where the
// precision budget allows: warp MLP (xn tolerance ~1e-3 cells) and base MLP
// (outputs O(1e-4))). f32 LDS out, in-place (proven R7).
// ---------------------------------------------------------------------------
template<int KSTEPS, int NTILES, int TERMS, bool RELU>
__device__ __forceinline__ void wave_layer(float* X,
                                           const unsigned short* __restrict__ wfrag, int cbase,
                                           int wrow, int lane)
{
    f32x4 acc[2][NTILES];
#pragma unroll
    for (int ms = 0; ms < 2; ++ms)
#pragma unroll
        for (int t = 0; t < NTILES; ++t) acc[ms][t] = f32x4{0.f, 0.f, 0.f, 0.f};
    const int r15 = lane & 15, q = lane >> 4;
    const short8* wf8 = reinterpret_cast<const short8*>(wfrag) + (size_t)cbase * 128;
#pragma unroll
    for (int s = 0; s < KSTEPS; ++s) {
        short8 ah[2], al[2];
#pragma unroll
        for (int ms = 0; ms < 2; ++ms) {
            const float* xp = X + (size_t)(wrow + ms * 16 + r15) * LDW + s * 32 + q * 8;
            const f32x4 x0 = reinterpret_cast<const f32x4*>(xp)[0];
            const f32x4 x1 = reinterpret_cast<const f32x4*>(xp)[1];
            union { unsigned u[4]; short8 s8; } uh, ul;
            if (TERMS == 3) {
                split_pair(x0[0], x0[1], uh.u[0], ul.u[0]);
                split_pair(x0[2], x0[3], uh.u[1], ul.u[1]);
                split_pair(x1[0], x1[1], uh.u[2], ul.u[2]);
                split_pair(x1[2], x1[3], uh.u[3], ul.u[3]);
                al[ms] = ul.s8;
            } else {
                uh.u[0] = cvt_pk_bf16(x0[0], x0[1]);
                uh.u[1] = cvt_pk_bf16(x0[2], x0[3]);
                uh.u[2] = cvt_pk_bf16(x1[0], x1[1]);
                uh.u[3] = cvt_pk_bf16(x1[2], x1[3]);
            }
            ah[ms] = uh.s8;
        }
#pragma unroll
        for (int t = 0; t < NTILES; ++t) {
            const short8* cp = wf8 + (size_t)(s * NTILES + t) * 128;
            const short8 bh = cp[lane];
            short8 bl;
            if (TERMS == 3) bl = cp[64 + lane];
#pragma unroll
            for (int ms = 0; ms < 2; ++ms) {
                acc[ms][t] = __builtin_amdgcn_mfma_f32_16x16x32_bf16(ah[ms], bh, acc[ms][t], 0, 0, 0);
                if (TERMS == 3) {
                    acc[ms][t] = __builtin_amdgcn_mfma_f32_16x16x32_bf16(al[ms], bh, acc[ms][t], 0, 0, 0);
                    acc[ms][t] = __builtin_amdgcn_mfma_f32_16x16x32_bf16(ah[ms], bl, acc[ms][t], 0, 0, 0);
                }
            }
        }
    }
#pragma unroll
    for (int ms = 0; ms < 2; ++ms)
#pragma unroll
        for (int t = 0; t < NTILES; ++t)
#pragma unroll
            for (int r = 0; r < 4; ++r) {
                float v = acc[ms][t][r];
                if (RELU) v = fmaxf(v, 0.f);
                X[(size_t)(wrow + ms * 16 + q * 4 + r) * LDW + t * 16 + r15] = v;
            }
}

// ---------------------------------------------------------------------------
// Kernel 1: freq encode + warp MLP (single-term MFMA) -> xn4 + DENSE levels.
// Per-wave epilogue (no final barrier, proven R13).
// ---------------------------------------------------------------------------
__global__ __launch_bounds__(256, 4) void k_warp_mfma(
    const float* __restrict__ g_pos, const float* __restrict__ g_t,
    const float* __restrict__ g_tab,
    const unsigned short* __restrict__ wfrag,
    float* __restrict__ xn4,
    unsigned* __restrict__ featp, size_t stride, int N, int n_dense, LevelParams lp)
{
    __shared__ float buf[128 * LDW];        // 34.8 KB
    const int tid = threadIdx.x;
    const int base = blockIdx.x * 128;
    const int p = tid & 127;
    const int pn = min(base + p, N - 1);
    const float PI_F = 3.14159265358979323846f;

    {   // enc staging: thread-pairs split the 4 input dims
        const int dpair = tid >> 7;
        float v0, v1;
        if (dpair == 0) { v0 = g_pos[3 * pn + 0]; v1 = g_pos[3 * pn + 1]; }
        else            { v0 = g_pos[3 * pn + 2]; v1 = g_t[pn]; }
#pragma unroll
        for (int e = 0; e < 2; ++e) {
            const float x = e ? v1 : v0;
            const int d = dpair * 2 + e;
            f32x4 sv, cv;
#pragma unroll
            for (int k = 0; k < 4; ++k) {
                const float a = x * (PI_F * (float)(1 << k));
                sv[k] = __sinf(a);
                cv[k] = __cosf(a);
            }
            *reinterpret_cast<f32x4*>(&buf[(size_t)p * LDW + d * 8])     = sv;
            *reinterpret_cast<f32x4*>(&buf[(size_t)p * LDW + d * 8 + 4]) = cv;
        }
    }
    __syncthreads();
    const int lane = tid & 63, wrow = (tid >> 6) * 32;
    wave_layer<1, 4, 1, true >(buf, wfrag, C_W0, wrow, lane);
    wave_layer<2, 4, 1, true >(buf, wfrag, C_W1, wrow, lane);
    wave_layer<2, 1, 1, false>(buf, wfrag, C_W2, wrow, lane);
    // NO final barrier: epilogue reads only this wave's rows (same-wave DS order)

    const int prow = wrow + (lane & 31);
    const int sub  = lane >> 5;
    const int n = base + prow;
    const int pn2 = min(n, N - 1);
    const float ox = buf[(size_t)prow * LDW + 0];
    const float oy = buf[(size_t)prow * LDW + 1];
    const float oz = buf[(size_t)prow * LDW + 2];
    const float xnv[3] = { (g_pos[3 * pn2 + 0] + ox * MOVE_STEP + 1.5f) / 3.0f,
                           (g_pos[3 * pn2 + 1] + oy * MOVE_STEP + 1.5f) / 3.0f,
                           (g_pos[3 * pn2 + 2] + oz * MOVE_STEP + 1.5f) / 3.0f };
    if (sub == 0 && n < N) {
        reinterpret_cast<f32x4*>(xn4)[n] = f32x4{ xnv[0], xnv[1], xnv[2], 0.f };
    }

    const int dmid = min(3, n_dense);
    const int l0 = sub ? dmid : 0;
    const int l1 = sub ? n_dense : dmid;
    for (int l = l0; l < l1; ++l) {
        const float scale = lp.scale[l];
        const int res = lp.res[l];
        float fr[3]; int c0[3];
#pragma unroll
        for (int d = 0; d < 3; ++d) {
            const float pp = xnv[d] * scale + 0.5f;
            const float fl = floorf(pp);
            fr[d] = pp - fl;
            c0[d] = (int)fl;
        }
        const float* __restrict__ tbl = g_tab + (size_t)l * (size_t)(TBL * 2);
        f32x4u v[4];
#pragma unroll
        for (int pc = 0; pc < 4; ++pc) {
            const int cj = pc >> 1, ck = pc & 1;
            const int idx = c0[0] + res * ((c0[1] + cj) + res * (c0[2] + ck));
            v[pc] = *reinterpret_cast<const f32x4u*>(tbl + (size_t)idx * 2);
        }
        float f0 = 0.f, f1 = 0.f;
        const float wx0 = 1.f - fr[0], wx1 = fr[0];
#pragma unroll
        for (int pc = 0; pc < 4; ++pc) {
            const int cj = pc >> 1, ck = pc & 1;
            const float wyz = (cj ? fr[1] : 1.f - fr[1]) * (ck ? fr[2] : 1.f - fr[2]);
            f0 = fmaf(wx0 * wyz, v[pc][0], f0);
            f1 = fmaf(wx0 * wyz, v[pc][1], f1);
            f0 = fmaf(wx1 * wyz, v[pc][2], f0);
            f1 = fmaf(wx1 * wyz, v[pc][3], f1);
        }
        if (n < N) {
            __builtin_nontemporal_store(pk(f2bf(f0), f2bf(f1)), &featp[(size_t)l * stride + n]);
        }
    }
}

// ---------------------------------------------------------------------------
// Kernel 2 (bf16 tables): all hashed levels, level = blockIdx.y.
// uint4 x-pair trick (avg 5 gathers/pt-level), batches of 2 points. (R13)
// ---------------------------------------------------------------------------
__global__ __launch_bounds__(HTPB) void k_hash_all16(
    const unsigned* __restrict__ tab16,
    const float* __restrict__ xn4,
    unsigned* __restrict__ featp, size_t stride, int N, int n_dense, LevelParams lp)
{
    const int l = n_dense + blockIdx.y;
    const float scale = lp.scale[l];
    const unsigned* __restrict__ tbl = tab16 + (size_t)blockIdx.y * TBL;
    unsigned* __restrict__ op = featp + (size_t)l * stride;

    const int base = blockIdx.x * (HTPB * HPTS) + threadIdx.x;

#pragma unroll
    for (int b = 0; b < HPTS; b += 2) {
        int nn[2]; bool av[2];
        f32x4 xs[2];
#pragma unroll
        for (int j = 0; j < 2; ++j) {
            nn[j] = base + (b + j) * HTPB;
            av[j] = nn[j] < N;
            xs[j] = reinterpret_cast<const f32x4*>(xn4)[av[j] ? nn[j] : 0];
        }

        float frx[2];
        float wyz[2][4];
        uint4 w4[2][4];
        unsigned vodd[2][4] = {};
        unsigned a3p[2], mm[2];
        bool far_[2];
#pragma unroll
        for (int j = 0; j < 2; ++j) {
            int c0[3]; float fr[3];
#pragma unroll
            for (int d = 0; d < 3; ++d) {
                const float pp = xs[j][d] * scale + 0.5f;
                const float fl = floorf(pp);
                fr[d] = pp - fl;
                c0[d] = (int)fl;
            }
            frx[j] = fr[0];
            const unsigned ux  = (unsigned)c0[0];
            const unsigned ry0 = (unsigned)c0[1] * 2654435761u;
            const unsigned ry1 = (unsigned)(c0[1] + 1) * 2654435761u;
            const unsigned rz0 = (unsigned)c0[2] * 805459861u;
            const unsigned rz1 = (unsigned)(c0[2] + 1) * 805459861u;
            mm[j]  = ux ^ (ux + 1u);
            far_[j] = mm[j] > 3u;
            const float wy0 = 1.f - fr[1], wy1 = fr[1];
            const float wz0 = 1.f - fr[2], wz1 = fr[2];
            wyz[j][0] = wy0 * wz0; wyz[j][1] = wy0 * wz1;
            wyz[j][2] = wy1 * wz0; wyz[j][3] = wy1 * wz1;
            const unsigned rr[4] = { ry0 ^ rz0, ry0 ^ rz1, ry1 ^ rz0, ry1 ^ rz1 };
            unsigned a3 = 0;
#pragma unroll
            for (int pc = 0; pc < 4; ++pc) {
                const unsigned iA = (ux ^ rr[pc]) & (TBL - 1u);
                a3 |= (iA & 3u) << (2 * pc);
                w4[j][pc] = *reinterpret_cast<const uint4*>(tbl + (iA & ~3u));
            }
            a3p[j] = a3;
            if (far_[j]) {
#pragma unroll
                for (int pc = 0; pc < 4; ++pc) {
                    const unsigned iB = ((ux + 1u) ^ rr[pc]) & (TBL - 1u);
                    vodd[j][pc] = tbl[iB];
                }
            }
        }

#pragma unroll
        for (int j = 0; j < 2; ++j) {
            float f0 = 0.f, f1 = 0.f;
            const float wx0 = 1.f - frx[j], wx1 = frx[j];
#pragma unroll
            for (int pc = 0; pc < 4; ++pc) {
                const unsigned a3 = (a3p[j] >> (2 * pc)) & 3u;
                const unsigned vA = sel4(w4[j][pc], a3);
                const unsigned vB = far_[j] ? vodd[j][pc] : sel4(w4[j][pc], a3 ^ mm[j]);
                const float wA = wx0 * wyz[j][pc];
                const float wB = wx1 * wyz[j][pc];
                f0 = fmaf(wA, bf2f((unsigned short)(vA & 0xffffu)), f0);
                f1 = fmaf(wA, bf2f((unsigned short)(vA >> 16)), f1);
                f0 = fmaf(wB, bf2f((unsigned short)(vB & 0xffffu)), f0);
                f1 = fmaf(wB, bf2f((unsigned short)(vB >> 16)), f1);
            }
            if (av[j]) __builtin_nontemporal_store(pk(f2bf(f0), f2bf(f1)), &op[nn[j]]);
        }
    }
}

// ---------------------------------------------------------------------------
// Kernel 3: base MLP (single-term) + SH + head MLP (3-term) -> output
// ---------------------------------------------------------------------------
__global__ __launch_bounds__(256, 4) void k_final_mfma(
    const unsigned* __restrict__ featp, size_t stride,
    const float* __restrict__ xn4,
    const float* __restrict__ g_dir,
    const unsigned short* __restrict__ wfrag,
    float* __restrict__ g_out, int N)
{
    __shared__ float buf[128 * LDW];        // 34.8 KB
    const int tid = threadIdx.x;
    const int base = blockIdx.x * 128;
    const int p = tid & 127;
    const int pn = min(base + p, N - 1);
    const int g = tid >> 7;

    // stage 16 packed feat planes -> buf[p][0..31] (unpack bf16 -> f32)
#pragma unroll
    for (int j = 0; j < 8; ++j) {
        const int l = g * 8 + j;
        const unsigned v = __builtin_nontemporal_load(&featp[(size_t)l * stride + pn]);
        buf[(size_t)p * LDW + 2 * l]     = bf2f((unsigned short)(v & 0xffffu));
        buf[(size_t)p * LDW + 2 * l + 1] = bf2f((unsigned short)(v >> 16));
    }
    __syncthreads();

    const int lane = tid & 63, wrow = (tid >> 6) * 32;
    wave_layer<1, 4, 1, true >(buf, wfrag, C_B0, wrow, lane);
    wave_layer<2, 1, 1, false>(buf, wfrag, C_B1, wrow, lane);
    __syncthreads();

    float density = 0.f;
    if (tid < 128) {
        float bb[16];
        const f32x4* bv = reinterpret_cast<const f32x4*>(&buf[(size_t)tid * LDW]);
#pragma unroll
        for (int g4 = 0; g4 < 4; ++g4) {
            const f32x4 v = bv[g4];
#pragma unroll
            for (int j = 0; j < 4; ++j) bb[4 * g4 + j] = v[j];
        }
        const f32x4 xv = reinterpret_cast<const f32x4*>(xn4)[pn];
        const bool sel = xv[0] > 0.f && xv[0] < 1.f && xv[1] > 0.f && xv[1] < 1.f &&
                         xv[2] > 0.f && xv[2] < 1.f;
        density = sel ? expf(bb[0] - 1.0f) : 0.0f;

        const float ddx = g_dir[3 * pn + 0];
        const float ddy = g_dir[3 * pn + 1];
        const float ddz = g_dir[3 * pn + 2];
        const float nrm = sqrtf(ddx * ddx + ddy * ddy + ddz * ddz);
        const float x = ddx / nrm, y = ddy / nrm, z = ddz / nrm;
        const float xy = x * y, yz = y * z, xz = x * z;
        const float x2 = x * x, y2 = y * y, z2 = z * z;
        f32x4 o0, o1, o2, o3, o4, o5, o6, o7;
        o0[0] = 0.28209479177387814f;
        o0[1] = -0.48860251190291987f * y;
        o0[2] = 0.48860251190291987f * z;
        o0[3] = -0.48860251190291987f * x;
        o1[0] = 1.0925484305920792f * xy;
        o1[1] = -1.0925484305920792f * yz;
        o1[2] = 0.94617469575756f * z2 - 0.31539156525252f;
        o1[3] = -1.0925484305920792f * xz;
        o2[0] = 0.5462742152960396f * (x2 - y2);
        o2[1] = 0.5900435899266435f * y * (y2 - 3.0f * x2);
        o2[2] = 2.890611442640554f * xy * z;
        o2[3] = 0.4570457994644657f * y * (1.0f - 5.0f * z2);
        o3[0] = 0.3731763325901154f * z * (5.0f * z2 - 3.0f);
        o3[1] = 0.4570457994644657f * x * (1.0f - 5.0f * z2);
        o3[2] = 1.445305721320277f * z * (x2 - y2);
        o3[3] = 0.5900435899266435f * x * (3.0f * y2 - x2);
        o4[0] = bb[1];  o4[1] = bb[2];  o4[2] = bb[3];  o4[3] = bb[4];
        o5[0] = bb[5];  o5[1] = bb[6];  o5[2] = bb[7];  o5[3] = bb[8];
        o6[0] = bb[9];  o6[1] = bb[10]; o6[2] = bb[11]; o6[3] = bb[12];
        o7[0] = bb[13]; o7[1] = bb[14]; o7[2] = bb[15]; o7[3] = 0.f;
        f32x4* wb = reinterpret_cast<f32x4*>(&buf[(size_t)tid * LDW]);
        wb[0] = o0; wb[1] = o1; wb[2] = o2; wb[3] = o3;
        wb[4] = o4; wb[5] = o5; wb[6] = o6; wb[7] = o7;
    }
    __syncthreads();

    wave_layer<1, 4, 3, true >(buf, wfrag, C_H0, wrow, lane);
    wave_layer<2, 4, 3, true >(buf, wfrag, C_H1, wrow, lane);
    wave_layer<2, 1, 3, false>(buf, wfrag, C_H2, wrow, lane);
    __syncthreads();

    if (tid < 128 && base + tid < N) {
        const int n = base + tid;
        float4 o;
        o.x = 1.0f / (1.0f + expf(-buf[(size_t)tid * LDW + 0]));
        o.y = 1.0f / (1.0f + expf(-buf[(size_t)tid * LDW + 1]));
        o.z = 1.0f / (1.0f + expf(-buf[(size_t)tid * LDW + 2]));
        o.w = density;
        *reinterpret_cast<float4*>(g_out + (size_t)n * 4) = o;
    }
}

// ---------------------------------------------------------------------------
// Scalar fallback (round-2 monolith) used only if ws too small
// ---------------------------------------------------------------------------
template<int IN, int OUT, bool RELU>
__device__ __forceinline__ void layer(const float* __restrict__ W,
                                      const float* __restrict__ hin,
                                      float* __restrict__ A,
                                      float* __restrict__ out)
{
#pragma unroll
    for (int j = 0; j < OUT; ++j) out[j] = 0.f;
#pragma unroll
    for (int c = 0; c < IN; c += CHUNK) {
#pragma unroll
        for (int i = 0; i < CHUNK; ++i) {
            if (c + i < IN) A[i * TPB] = RELU ? fmaxf(hin[c + i], 0.f) : hin[c + i];
        }
        const int cnt = (IN - c < CHUNK) ? (IN - c) : CHUNK;
#pragma unroll 4
        for (int i = 0; i < cnt; ++i) {
            const float a = A[i * TPB];
            const float* __restrict__ Wr = W + (size_t)(c + i) * OUT;
#pragma unroll
            for (int j = 0; j < OUT; ++j)
                out[j] = fmaf(a, Wr[j], out[j]);
        }
    }
}

__global__ __launch_bounds__(TPB, 4) void dngp_mono(
    const float* __restrict__ g_pos, const float* __restrict__ g_t,
    const float* __restrict__ g_dir, const float* __restrict__ g_tab,
    const float* __restrict__ Ww0, const float* __restrict__ Ww1, const float* __restrict__ Ww2,
    const float* __restrict__ Wb0, const float* __restrict__ Wb1,
    const float* __restrict__ Wh0, const float* __restrict__ Wh1, const float* __restrict__ Wh2,
    float* __restrict__ g_out, int N, LevelParams lp)
{
    __shared__ float s_act[CHUNK * TPB];
    const int tid = threadIdx.x;
    const int n = blockIdx.x * TPB + tid;
    if (n >= N) return;
    float* __restrict__ A = s_act + tid;

    const float px = g_pos[3 * n + 0];
    const float py = g_pos[3 * n + 1];
    const float pz = g_pos[3 * n + 2];
    const float tt = g_t[n];

    float enc[32];
    {
        const float xin[4] = { px, py, pz, tt };
        const float PI_F = 3.14159265358979323846f;
#pragma unroll
        for (int d = 0; d < 4; ++d)
#pragma unroll
            for (int k = 0; k < 4; ++k) {
                float s, c;
                sincosf(xin[d] * (PI_F * (float)(1 << k)), &s, &c);
                enc[d * 8 + k]     = s;
                enc[d * 8 + 4 + k] = c;
            }
    }

    float h[64], h2[64], off[3];
    layer<32, 64, false>(Ww0, enc, A, h);
    layer<64, 64, true >(Ww1, h,   A, h2);
    layer<64, 3,  true >(Ww2, h2,  A, off);

    const float xn[3] = { (px + off[0] * MOVE_STEP + 1.5f) / 3.0f,
                          (py + off[1] * MOVE_STEP + 1.5f) / 3.0f,
                          (pz + off[2] * MOVE_STEP + 1.5f) / 3.0f };
    const bool sel = xn[0] > 0.f && xn[0] < 1.f && xn[1] > 0.f && xn[1] < 1.f &&
                     xn[2] > 0.f && xn[2] < 1.f;

    float feat[32];
#pragma unroll 2
    for (int l = 0; l < N_LVL; ++l) {
        const float scale = lp.scale[l];
        const int res = lp.res[l];
        float fr[3]; int c0[3];
#pragma unroll
        for (int d = 0; d < 3; ++d) {
            const float pp = xn[d] * scale + 0.5f;
            const float fl = floorf(pp);
            fr[d] = pp - fl;
            c0[d] = (int)fl;
        }
        const float* __restrict__ tbl = g_tab + (size_t)l * (size_t)(TBL * 2);
        float f0 = 0.f, f1 = 0.f;
        if (lp.dense[l]) {
#pragma unroll
            for (int c = 0; c < 8; ++c) {
                const int ci = (c >> 2) & 1, cj = (c >> 1) & 1, ck = c & 1;
                const unsigned idx = (unsigned)((c0[0] + ci) + res * ((c0[1] + cj) + res * (c0[2] + ck)));
                const float2 f = *reinterpret_cast<const float2*>(tbl + (size_t)idx * 2);
                const float w = (ci ? fr[0] : 1.f - fr[0]) * (cj ? fr[1] : 1.f - fr[1]) * (ck ? fr[2] : 1.f - fr[2]);
                f0 = fmaf(w, f.x, f0);
                f1 = fmaf(w, f.y, f1);
            }
        } else {
#pragma unroll
            for (int c = 0; c < 8; ++c) {
                const int ci = (c >> 2) & 1, cj = (c >> 1) & 1, ck = c & 1;
                const unsigned hx = (unsigned)(c0[0] + ci);
                const unsigned hy = (unsigned)(c0[1] + cj) * 2654435761u;
                const unsigned hz = (unsigned)(c0[2] + ck) * 805459861u;
                const unsigned idx = (hx ^ hy ^ hz) & (TBL - 1u);
                const float2 f = *reinterpret_cast<const float2*>(tbl + (size_t)idx * 2);
                const float w = (ci ? fr[0] : 1.f - fr[0]) * (cj ? fr[1] : 1.f - fr[1]) * (ck ? fr[2] : 1.f - fr[2]);
                f0 = fmaf(w, f.x, f0);
                f1 = fmaf(w, f.y, f1);
            }
        }
        feat[2 * l]     = f0;
        feat[2 * l + 1] = f1;
    }

    layer<32, 64, false>(Wb0, feat, A, h);
    float b[16];
    layer<64, 16, true >(Wb1, h, A, b);
    const float density = sel ? expf(b[0] - 1.0f) : 0.0f;

    float hin[31];
    {
        const float ddx = g_dir[3 * n + 0];
        const float ddy = g_dir[3 * n + 1];
        const float ddz = g_dir[3 * n + 2];
        const float nrm = sqrtf(ddx * ddx + ddy * ddy + ddz * ddz);
        const float x = ddx / nrm, y = ddy / nrm, z = ddz / nrm;
        const float xy = x * y, yz = y * z, xz = x * z;
        const float x2_ = x * x, y2 = y * y, z2 = z * z;
        hin[0]  = 0.28209479177387814f;
        hin[1]  = -0.48860251190291987f * y;
        hin[2]  = 0.48860251190291987f * z;
        hin[3]  = -0.48860251190291987f * x;
        hin[4]  = 1.0925484305920792f * xy;
        hin[5]  = -1.0925484305920792f * yz;
        hin[6]  = 0.94617469575756f * z2 - 0.31539156525252f;
        hin[7]  = -1.0925484305920792f * xz;
        hin[8]  = 0.5462742152960396f * (x2_ - y2);
        hin[9]  = 0.5900435899266435f * y * (y2 - 3.0f * x2_);
        hin[10] = 2.890611442640554f * xy * z;
        hin[11] = 0.4570457994644657f * y * (1.0f - 5.0f * z2);
        hin[12] = 0.3731763325901154f * z * (5.0f * z2 - 3.0f);
        hin[13] = 0.4570457994644657f * x * (1.0f - 5.0f * z2);
        hin[14] = 1.445305721320277f * z * (x2_ - y2);
        hin[15] = 0.5900435899266435f * x * (3.0f * y2 - x2_);
#pragma unroll
        for (int j = 0; j < 15; ++j) hin[16 + j] = b[1 + j];
    }

    layer<31, 64, false>(Wh0, hin, A, h);
    layer<64, 64, true >(Wh1, h,   A, h2);
    float rgb[3];
    layer<64, 3,  true >(Wh2, h2,  A, rgb);

    float4 o;
    o.x = 1.0f / (1.0f + expf(-rgb[0]));
    o.y = 1.0f / (1.0f + expf(-rgb[1]));
    o.z = 1.0f / (1.0f + expf(-rgb[2]));
    o.w = density;
    *reinterpret_cast<float4*>(g_out + (size_t)n * 4) = o;
}

extern "C" void kernel_launch(void* const* d_in, const int* in_sizes, int n_in,
                              void* d_out, int out_size, void* d_ws, size_t ws_size,
                              hipStream_t stream)
{
    const float* g_pos = (const float*)d_in[0];
    const float* g_t   = (const float*)d_in[1];
    const float* g_dir = (const float*)d_in[2];
    const float* g_tab = (const float*)d_in[3];
    const float* Ww0   = (const float*)d_in[4];
    const float* Ww1   = (const float*)d_in[5];
    const float* Ww2   = (const float*)d_in[6];
    const float* Wb0   = (const float*)d_in[7];
    const float* Wb1   = (const float*)d_in[8];
    const float* Wh0   = (const float*)d_in[9];
    const float* Wh1   = (const float*)d_in[10];
    const float* Wh2   = (const float*)d_in[11];
    const int N = in_sizes[0] / 3;

    LevelParams lp;
    int n_dense = 0;
    const double Bv = exp(log(4096.0 / 16.0) / 15.0);
    for (int l = 0; l < N_LVL; ++l) {
        const double s = 16.0 * pow(Bv, (double)l) - 1.0;
        lp.scale[l] = (float)s;
        const int r = (int)ceil(s) + 1;
        lp.res[l] = r;
        lp.dense[l] = ((long long)r * r * r <= (long long)TBL) ? 1 : 0;
        if (lp.dense[l]) n_dense = l + 1;
    }
    const int n_hashed = N_LVL - n_dense;

    const size_t stride = ((size_t)N + 259) & ~(size_t)3;
    const size_t ws_need = (size_t)C_TOT * 2048
                         + stride * 4 * 4              // xn4 plane (float4)
                         + stride * 4 * 16             // 16 packed feat planes
                         + (size_t)n_hashed * TBL * 4; // bf16x2 tables

    if (ws_size >= ws_need) {
        unsigned short* wfrag = (unsigned short*)d_ws;
        float* xn4 = (float*)((char*)d_ws + (size_t)C_TOT * 2048);
        unsigned* featp = (unsigned*)(xn4 + 4 * stride);
        unsigned* tab16 = featp + 16 * stride;

        AllLayers al;
        al.L[0] = { Ww0, 32, 64, 1, 4, C_W0 };
        al.L[1] = { Ww1, 64, 64, 2, 4, C_W1 };
        al.L[2] = { Ww2, 64,  3, 2, 1, C_W2 };
        al.L[3] = { Wb0, 32, 64, 1, 4, C_B0 };
        al.L[4] = { Wb1, 64, 16, 2, 1, C_B1 };
        al.L[5] = { Wh0, 31, 64, 1, 4, C_H0 };
        al.L[6] = { Wh1, 64, 64, 2, 4, C_H1 };
        al.L[7] = { Wh2, 64,  3, 2, 1, C_H2 };

        const int nchunk = (N + HTPB * HPTS - 1) / (HTPB * HPTS);

        dim3 mgrid((N + 127) / 128), mblock(256);
        dim3 hgrid(nchunk, n_hashed), hblock(HTPB);

        hipLaunchKernelGGL(k_prep, dim3(8), dim3(256), 0, stream, al, wfrag);
        hipLaunchKernelGGL(k_tab16, dim3(2048), dim3(256), 0, stream,
                           g_tab, tab16, n_dense, n_hashed);

        hipLaunchKernelGGL(k_warp_mfma, mgrid, mblock, 0, stream,
                           g_pos, g_t, g_tab, wfrag, xn4,
                           featp, stride, N, n_dense, lp);

        hipLaunchKernelGGL(k_hash_all16, hgrid, hblock, 0, stream,
                           tab16, xn4, featp, stride, N, n_dense, lp);

        hipLaunchKernelGGL(k_final_mfma, mgrid, mblock, 0, stream,
                           featp, stride, xn4, g_dir,
                           wfrag, (float*)d_out, N);
    } else {
        dim3 grid((N + TPB - 1) / TPB), block(TPB);
        hipLaunchKernelGGL(dngp_mono, grid, block, 0, stream,
                           g_pos, g_t, g_dir, g_tab,
                           Ww0, Ww1, Ww2, Wb0, Wb1, Wh0, Wh1, Wh2,
                           (float*)d_out, N, lp);
    }
}